// Round 2
// baseline (904.529 us; speedup 1.0000x reference)
//
#include <hip/hip_runtime.h>
#include <hip/hip_bf16.h>
#include <math.h>

typedef __bf16 bf16;
typedef bf16 bf16x8 __attribute__((ext_vector_type(8)));
typedef bf16 bf16x4 __attribute__((ext_vector_type(4)));
typedef float f32x4 __attribute__((ext_vector_type(4)));

#define MFMA16(a, b, c) __builtin_amdgcn_mfma_f32_16x16x32_bf16(a, b, c, 0, 0, 0)

// XOR-swizzle on 16B chunks within a row: breaks power-of-2 row-stride bank aliasing.
__device__ __forceinline__ uint32_t swz(uint32_t base, uint32_t row, uint32_t rs, uint32_t cb) {
    return base + row * rs + (((cb >> 4) ^ (row & 7u)) << 4) + (cb & 15u);
}

// async global->LDS, 16B per lane. LDS dest = wave-uniform base + lane*16 (linear).
__device__ __forceinline__ void gload16(const void* g, void* l) {
    __builtin_amdgcn_global_load_lds((const __attribute__((address_space(1))) void*)g,
                                     (__attribute__((address_space(3))) void*)l, 16, 0, 0);
}

// Scratch map (row r = one of 32768 tokens):
//  src  slice r*2048B: [0,1024)=x_bf16 (xcvt; dead after outproj) -> h[1024:1536]
//                      [1024,2048)=x1 bf16 (outproj; read ff1, ff2-residual)
//  dout slice r*2048B: [0,1024)=k, [1024,2048)=v (qkv; dead after attn)
//                      -> h[0:1024] (ff1) -> final f32 out row (ff2, after h consumed)
//  ws: [0,6.3MB)=bf16 weights; [6.3,39.8MB) r*1024B: q (qkv) -> O (attn, same
//      block/cols) -> h[1536:2048] (ff1)

// ---------- weights f32 -> bf16 ----------
__global__ void wcvt_kernel(const float* __restrict__ w0, const float* __restrict__ w1,
                            const float* __restrict__ w2, const float* __restrict__ w3,
                            bf16* __restrict__ o) {
    int i = blockIdx.x * blockDim.x + threadIdx.x;
    int e = i * 4;
    const float* s;
    int off;
    if (e < 786432)       { s = w0; off = e; }
    else if (e < 1048576) { s = w1; off = e - 786432; }
    else if (e < 2097152) { s = w2; off = e - 1048576; }
    else                  { s = w3; off = e - 2097152; }
    float4 v = *(const float4*)(s + off);
    bf16x4 h = { (bf16)v.x, (bf16)v.y, (bf16)v.z, (bf16)v.w };
    *(bf16x4*)(o + e) = h;
}

// ---------- src f32 -> bf16 in place (row-aligned slot; wave per row) ----------
__global__ void xcvt_kernel(float* __restrict__ src) {
    int row = blockIdx.x * 4 + (threadIdx.x >> 6);
    int l = threadIdx.x & 63;
    float* rp = src + (size_t)row * 512 + l * 8;
    float4 v0 = *(const float4*)rp;
    float4 v1 = *(const float4*)(rp + 4);
    asm volatile("s_waitcnt vmcnt(0)" ::: "memory");  // all wave reads before any write
    bf16x8 h = { (bf16)v0.x, (bf16)v0.y, (bf16)v0.z, (bf16)v0.w,
                 (bf16)v1.x, (bf16)v1.y, (bf16)v1.z, (bf16)v1.w };
    *(bf16x8*)((bf16*)(src + (size_t)row * 512) + l * 8) = h;
}

// ---------- qkv GEMM: M=32768 N=1536 K=512, 128x128 tiles ----------
extern "C" __global__ __launch_bounds__(256, 3)
void qkv_kernel(const char* __restrict__ xb, const bf16* __restrict__ Wqkv,
                const float* __restrict__ bqkv, char* __restrict__ qOb,
                char* __restrict__ kvb) {
    extern __shared__ char smem[];
    const int tid = threadIdx.x;
    const int wid = tid >> 6, lane = tid & 63, l16 = lane & 15, quad = lane >> 4;
    const int wm = wid >> 1, wn = wid & 1;
    const int rb = blockIdx.x, cb = blockIdx.y;
    f32x4 acc[4][4];
#pragma unroll
    for (int i = 0; i < 4; ++i)
#pragma unroll
        for (int nt = 0; nt < 4; ++nt) acc[i][nt] = (f32x4){0.f, 0.f, 0.f, 0.f};

#pragma unroll 1
    for (int kstep = 0; kstep < 8; ++kstep) {
        // stage B tile 128x64 bf16 -> LDS (swizzled, rs=128B)
        {
            int lr = tid >> 1, half = tid & 1;
            const char* g = (const char*)(Wqkv + (size_t)(cb * 128 + lr) * 512 + kstep * 64 + half * 32);
#pragma unroll
            for (int c = 0; c < 4; ++c) {
                bf16x8 v = *(const bf16x8*)(g + c * 16);
                *(bf16x8*)(smem + swz(0, lr, 128, half * 64 + c * 16)) = v;
            }
        }
        __syncthreads();
#pragma unroll
        for (int k16 = 0; k16 < 2; ++k16) {
            bf16x8 a[4];
#pragma unroll
            for (int i = 0; i < 4; ++i) {
                int row = rb * 128 + wm * 64 + i * 16 + l16;
                a[i] = *(const bf16x8*)(xb + (size_t)row * 2048 + (kstep * 64 + k16 * 32 + quad * 8) * 2);
            }
#pragma unroll
            for (int nt = 0; nt < 4; ++nt) {
                bf16x8 b = *(bf16x8*)(smem + swz(0, wn * 64 + nt * 16 + l16, 128, k16 * 64 + quad * 16));
#pragma unroll
                for (int i = 0; i < 4; ++i) acc[i][nt] = MFMA16(a[i], b, acc[i][nt]);
            }
        }
        __syncthreads();  // after last iter: B region dead -> transpose scratch
    }
    // ---- bias + C->rowmajor transpose through wave-private LDS (8KB/wave) ----
    const uint32_t wb = (uint32_t)wid * 8192;  // 64 rows x 128B
#pragma unroll
    for (int nt = 0; nt < 4; ++nt) {
        float bias = bqkv[cb * 128 + wn * 64 + nt * 16 + l16];
#pragma unroll
        for (int i = 0; i < 4; ++i)
#pragma unroll
            for (int r = 0; r < 4; ++r)
                *(bf16*)(smem + swz(wb, i * 16 + quad * 4 + r, 128, (nt * 16 + l16) * 2)) =
                    (bf16)(acc[i][nt][r] + bias);
    }
    asm volatile("s_waitcnt lgkmcnt(0)" ::: "memory");
    const int region = cb >> 2;  // 0=q, 1=k, 2=v (uniform per block)
#pragma unroll
    for (int c = 0; c < 8; ++c) {
        int lr = c * 8 + (lane >> 3), ch = lane & 7;
        bf16x8 v = *(bf16x8*)(smem + swz(wb, lr, 128, ch * 16));
        int row_g = rb * 128 + wm * 64 + lr;
        int colb = (cb * 128 + wn * 64) * 2 + ch * 16;  // byte col in 1536*2 space
        if (region == 0)      *(bf16x8*)(qOb + (size_t)row_g * 1024 + colb) = v;
        else if (region == 1) *(bf16x8*)(kvb + (size_t)row_g * 2048 + (colb - 1024)) = v;
        else                  *(bf16x8*)(kvb + (size_t)row_g * 2048 + 1024 + (colb - 2048)) = v;
    }
}

// ---------- attention: one block per (window, head) ----------
#define AVT 0u       // vT 64x128 bf16 rs=256B (16KB)
#define ASCR 16384u  // 8 waves x 2KB transpose scratch
extern "C" __global__ __launch_bounds__(512, 4)
void attn_kernel(char* __restrict__ qOb, const char* __restrict__ kvb) {
    extern __shared__ char smem[];
    const int tid = threadIdx.x;
    const int wid = tid >> 6, lane = tid & 63, l16 = lane & 15, quad = lane >> 4;
    const int win = blockIdx.x >> 3, head = blockIdx.x & 7;
    const size_t wrow0 = (size_t)win * 128;
    f32x4 zero4 = { 0.f, 0.f, 0.f, 0.f };

    // stage vT[dim][key] from v rows
    {
        int key = tid >> 2, d0 = (tid & 3) * 16;
        const char* vs = kvb + (wrow0 + key) * 2048 + 1024 + head * 128 + d0 * 2;
#pragma unroll
        for (int j = 0; j < 2; ++j) {
            bf16x8 v = *(const bf16x8*)(vs + j * 16);
#pragma unroll
            for (int e = 0; e < 8; ++e)
                *(bf16*)(smem + swz(AVT, d0 + j * 8 + e, 256, key * 2)) = v[e];
        }
    }
    __syncthreads();  // only barrier in this kernel

    // q fragments (A layout, direct from global)
    bf16x8 qf[2];
#pragma unroll
    for (int ks = 0; ks < 2; ++ks)
        qf[ks] = *(const bf16x8*)(qOb + (wrow0 + wid * 16 + l16) * 1024 + head * 128 + ks * 64 + quad * 16);

    // scores (k B-frags direct from global)
    f32x4 sa[8];
#pragma unroll
    for (int nt = 0; nt < 8; ++nt) sa[nt] = zero4;
#pragma unroll
    for (int nt = 0; nt < 8; ++nt)
#pragma unroll
        for (int ks = 0; ks < 2; ++ks) {
            bf16x8 kb = *(const bf16x8*)(kvb + (wrow0 + nt * 16 + l16) * 2048 + head * 128 + ks * 64 + quad * 16);
            sa[nt] = MFMA16(qf[ks], kb, sa[nt]);
        }
#pragma unroll
    for (int nt = 0; nt < 8; ++nt) sa[nt] *= 0.125f;
#pragma unroll
    for (int r = 0; r < 4; ++r) {
        float m = sa[0][r];
#pragma unroll
        for (int nt = 1; nt < 8; ++nt) m = fmaxf(m, sa[nt][r]);
#pragma unroll
        for (int sft = 1; sft < 16; sft <<= 1) m = fmaxf(m, __shfl_xor(m, sft, 64));
        float s = 0.f;
#pragma unroll
        for (int nt = 0; nt < 8; ++nt) {
            float e = __expf(sa[nt][r] - m);
            sa[nt][r] = e;
            s += e;
        }
#pragma unroll
        for (int sft = 1; sft < 16; sft <<= 1) s += __shfl_xor(s, sft, 64);
        float inv = 1.0f / s;
#pragma unroll
        for (int nt = 0; nt < 8; ++nt) sa[nt][r] *= inv;
    }

    // P C->A transpose through wave-private scratch
    const uint32_t sb = ASCR + (uint32_t)wid * 2048;
    bf16x8 pf[4];
#pragma unroll
    for (int hf = 0; hf < 2; ++hf) {
#pragma unroll
        for (int nt = 0; nt < 4; ++nt)
#pragma unroll
            for (int r = 0; r < 4; ++r)
                *(bf16*)(smem + swz(sb, quad * 4 + r, 128, (nt * 16 + l16) * 2)) = (bf16)sa[hf * 4 + nt][r];
        asm volatile("s_waitcnt lgkmcnt(0)" ::: "memory");
#pragma unroll
        for (int ks = 0; ks < 2; ++ks)
            pf[hf * 2 + ks] = *(bf16x8*)(smem + swz(sb, l16, 128, ks * 64 + quad * 16));
        asm volatile("s_waitcnt lgkmcnt(0)" ::: "memory");
    }

    // O = P @ V
    f32x4 ov[4];
#pragma unroll
    for (int nt = 0; nt < 4; ++nt) {
        ov[nt] = zero4;
#pragma unroll
        for (int ks = 0; ks < 4; ++ks) {
            bf16x8 vb = *(bf16x8*)(smem + swz(AVT, nt * 16 + l16, 256, ks * 64 + quad * 16));
            ov[nt] = MFMA16(pf[ks], vb, ov[nt]);
        }
    }
    // O store via transpose: two 32-col halves through 2KB wave scratch (rs=128)
#pragma unroll
    for (int hf = 0; hf < 2; ++hf) {
#pragma unroll
        for (int nt = 0; nt < 2; ++nt)
#pragma unroll
            for (int r = 0; r < 4; ++r)
                *(bf16*)(smem + swz(sb, quad * 4 + r, 128, (nt * 16 + l16) * 2)) = (bf16)ov[hf * 2 + nt][r];
        asm volatile("s_waitcnt lgkmcnt(0)" ::: "memory");
        {
            int row = lane >> 2, ch = lane & 3;
            bf16x8 v = *(bf16x8*)(smem + swz(sb, row, 128, ch * 16));
            *(bf16x8*)(qOb + (wrow0 + wid * 16 + row) * 1024 + head * 128 + hf * 64 + ch * 16) = v;
        }
        asm volatile("s_waitcnt lgkmcnt(0)" ::: "memory");
    }
}

// ---------- out-proj + residual + LN1: M=32768 N=512 K=512 ----------
extern "C" __global__ __launch_bounds__(256, 2)
void outproj_kernel(char* __restrict__ srcb, const char* __restrict__ qOb,
                    const bf16* __restrict__ Wout, const float* __restrict__ bout,
                    const float* __restrict__ g1, const float* __restrict__ be1) {
    extern __shared__ char smem[];
    const int tid = threadIdx.x;
    const int wid = tid >> 6, lane = tid & 63, l16 = lane & 15, quad = lane >> 4;
    const int mb = blockIdx.x;
    f32x4 acc[32];
#pragma unroll
    for (int nt = 0; nt < 32; ++nt) acc[nt] = (f32x4){0.f, 0.f, 0.f, 0.f};

#pragma unroll 1
    for (int kstep = 0; kstep < 8; ++kstep) {
        {
            int n0 = tid * 2;
#pragma unroll
            for (int rr = 0; rr < 2; ++rr) {
                int n = n0 + rr;
                const char* g = (const char*)(Wout + (size_t)n * 512 + kstep * 64);
#pragma unroll
                for (int c = 0; c < 8; ++c) {
                    bf16x8 v = *(const bf16x8*)(g + c * 16);
                    *(bf16x8*)(smem + swz(0, n, 128, c * 16)) = v;
                }
            }
        }
        __syncthreads();
#pragma unroll
        for (int k16 = 0; k16 < 2; ++k16) {
            bf16x8 a = *(const bf16x8*)(qOb + (size_t)(mb * 64 + wid * 16 + l16) * 1024 +
                                        (kstep * 64 + k16 * 32 + quad * 8) * 2);
#pragma unroll
            for (int nt = 0; nt < 32; ++nt) {
                bf16x8 b = *(bf16x8*)(smem + swz(0, nt * 16 + l16, 128, k16 * 64 + quad * 16));
                acc[nt] = MFMA16(a, b, acc[nt]);
            }
        }
        __syncthreads();  // after last iter: B region dead -> transpose scratch
    }
    // bias + residual (bf16 x) + LN1 (wave owns full row)
#pragma unroll
    for (int nt = 0; nt < 32; ++nt) {
        int col = nt * 16 + l16;
        float bb = bout[col];
#pragma unroll
        for (int r = 0; r < 4; ++r) {
            int row = mb * 64 + wid * 16 + quad * 4 + r;
            float xv = (float)*(const bf16*)(srcb + (size_t)row * 2048 + col * 2);
            acc[nt][r] += bb + xv;
        }
    }
    const uint32_t wb = (uint32_t)wid * 16384;  // 16 rows x 1024B
#pragma unroll
    for (int r = 0; r < 4; ++r) {
        float s = 0.f, s2 = 0.f;
#pragma unroll
        for (int nt = 0; nt < 32; ++nt) {
            float v = acc[nt][r];
            s += v;
            s2 += v * v;
        }
#pragma unroll
        for (int sft = 1; sft < 16; sft <<= 1) {
            s += __shfl_xor(s, sft, 64);
            s2 += __shfl_xor(s2, sft, 64);
        }
        float mu = s * (1.0f / 512.0f);
        float var = s2 * (1.0f / 512.0f) - mu * mu;
        float rstd = rsqrtf(var + 1e-5f);
#pragma unroll
        for (int nt = 0; nt < 32; ++nt) {
            int col = nt * 16 + l16;
            float v = (acc[nt][r] - mu) * rstd * g1[col] + be1[col];
            *(bf16*)(smem + swz(wb, quad * 4 + r, 1024, col * 2)) = (bf16)v;
        }
    }
    asm volatile("s_waitcnt lgkmcnt(0)" ::: "memory");
#pragma unroll
    for (int t = 0; t < 16; ++t) {
        int row = (t >> 2) * 4 + (lane >> 4);
        int ch = (t & 3) * 16 + l16;
        bf16x8 v = *(bf16x8*)(smem + swz(wb, row, 1024, ch * 16));
        *(bf16x8*)(srcb + (size_t)(mb * 64 + wid * 16 + row) * 2048 + 1024 + ch * 16) = v;
    }
}

// ---------- FF1 v2: M=32768 N=2048 K=512; 128x256 tile, 8 waves (2x4),
// wave tile 64x64 (4 A-frag x 4 B-frag per 16 MFMA); BK=32, 16 iters.
// B double-buffered via global_load_lds, [k-chunk][n] layout (conflict-free).
// A frags direct from global (x1 is L2/L3-resident; qkv-proven pattern).
// LDS 32KB -> 2 blocks/CU: cross-block TLP hides the barrier drain (m97 regime).
extern "C" __global__ __launch_bounds__(512, 4)
void ff1_kernel(char* __restrict__ srcb, const bf16* __restrict__ W1,
                const float* __restrict__ b1, char* __restrict__ doutb,
                char* __restrict__ wsOb) {
    extern __shared__ char smem[];
    const int tid = threadIdx.x;
    const int w = tid >> 6, lane = tid & 63, l16 = lane & 15, quad = lane >> 4;
    const int wm = w >> 2, wn = w & 3;
    const int mb = blockIdx.x, cb = blockIdx.y;
    const char* W1b = (const char*)W1;

    f32x4 acc[4][4];
#pragma unroll
    for (int i = 0; i < 4; ++i)
#pragma unroll
        for (int nt = 0; nt < 4; ++nt) acc[i][nt] = (f32x4){0.f, 0.f, 0.f, 0.f};

    // prologue: stage t=0 into buf0 (16 wave-issues of 1KB; 2 per wave)
#pragma unroll
    for (int j = 0; j < 2; ++j) {
        int idx = w * 2 + j, c = idx >> 2, ng = idx & 3;
        gload16(W1b + (size_t)(cb * 256 + ng * 64 + lane) * 1024 + c * 16,
                smem + c * 4096 + ng * 1024);
    }
    __syncthreads();

#pragma unroll 1
    for (int t = 0; t < 16; ++t) {
        if (t < 15) {
            const uint32_t nb = (uint32_t)((t + 1) & 1) * 16384u;
#pragma unroll
            for (int j = 0; j < 2; ++j) {
                int idx = w * 2 + j, c = idx >> 2, ng = idx & 3;
                gload16(W1b + (size_t)(cb * 256 + ng * 64 + lane) * 1024 + (t + 1) * 64 + c * 16,
                        smem + nb + c * 4096 + ng * 1024);
            }
        }
        const uint32_t B0 = (uint32_t)(t & 1) * 16384u;
        bf16x8 a[4];
#pragma unroll
        for (int i = 0; i < 4; ++i)
            a[i] = *(const bf16x8*)(srcb + (size_t)(mb * 128 + wm * 64 + i * 16 + l16) * 2048 +
                                    1024 + t * 64 + quad * 16);
#pragma unroll
        for (int nt = 0; nt < 4; ++nt) {
            bf16x8 b = *(bf16x8*)(smem + B0 + quad * 4096 + (wn * 64 + nt * 16 + l16) * 16);
#pragma unroll
            for (int i = 0; i < 4; ++i) acc[i][nt] = MFMA16(a[i], b, acc[i][nt]);
        }
        __syncthreads();  // drains this iter's prefetch; next buffer ready
    }

    // epilogue: bias+relu, per-i 16x64 transpose through 2KB wave scratch
    const uint32_t wb = (uint32_t)w * 2048u;  // in dead buf0 region
#pragma unroll
    for (int i = 0; i < 4; ++i) {
#pragma unroll
        for (int nt = 0; nt < 4; ++nt) {
            float bb = b1[cb * 256 + wn * 64 + nt * 16 + l16];
#pragma unroll
            for (int r = 0; r < 4; ++r)
                *(bf16*)(smem + swz(wb, quad * 4 + r, 128, (nt * 16 + l16) * 2)) =
                    (bf16)fmaxf(acc[i][nt][r] + bb, 0.0f);
        }
        asm volatile("s_waitcnt lgkmcnt(0)" ::: "memory");
#pragma unroll
        for (int t2 = 0; t2 < 2; ++t2) {
            int row = t2 * 8 + (lane >> 3), ch = lane & 7;
            bf16x8 v = *(bf16x8*)(smem + swz(wb, row, 128, ch * 16));
            size_t row_g = (size_t)(mb * 128 + wm * 64 + i * 16 + row);
            int cbyte = wn * 128 + ch * 16;  // within this cb's 512B slice
            if (cb < 4)      *(bf16x8*)(doutb + row_g * 2048 + cb * 512 + cbyte) = v;
            else if (cb < 6) *(bf16x8*)(srcb + row_g * 2048 + (cb - 4) * 512 + cbyte) = v;
            else             *(bf16x8*)(wsOb + row_g * 1024 + (cb - 6) * 512 + cbyte) = v;
        }
        asm volatile("s_waitcnt lgkmcnt(0)" ::: "memory");
    }
}

// ---------- FF2 v3 + residual + LN2: M=32768 N=512 K=2048 -> f32 out ----------
// 64x512 tile (grid 512), 8 waves, wave tile 64x64; BK=32, 64 iters.
// B (W2 k-panel) double-buffered via global_load_lds, [k-chunk][n] layout;
// A frags direct from global h (3-region). LDS 64KB -> 2 blocks/CU.
extern "C" __global__ __launch_bounds__(512, 4)
void ff2_kernel(char* __restrict__ doutb, const char* __restrict__ srcb,
                const char* __restrict__ wsOb, const bf16* __restrict__ W2,
                const float* __restrict__ b2, const float* __restrict__ g2,
                const float* __restrict__ be2) {
    extern __shared__ char smem[];
    const int tid = threadIdx.x;
    const int w = tid >> 6, lane = tid & 63, l16 = lane & 15, quad = lane >> 4;
    const int mb = blockIdx.x;
    const char* W2b = (const char*)W2;

    f32x4 acc[4][4];
#pragma unroll
    for (int i = 0; i < 4; ++i)
#pragma unroll
        for (int nt = 0; nt < 4; ++nt) acc[i][nt] = (f32x4){0.f, 0.f, 0.f, 0.f};

    // prologue: stage t=0 into buf0 (32 wave-issues of 1KB; 4 per wave)
#pragma unroll
    for (int j = 0; j < 4; ++j) {
        int idx = w * 4 + j, c = idx >> 3, ng = idx & 7;
        gload16(W2b + (size_t)(ng * 64 + lane) * 4096 + c * 16,
                smem + c * 8192 + ng * 1024);
    }
    __syncthreads();

#pragma unroll 1
    for (int t = 0; t < 64; ++t) {
        if (t < 63) {
            const uint32_t nb = (uint32_t)((t + 1) & 1) * 32768u;
#pragma unroll
            for (int j = 0; j < 4; ++j) {
                int idx = w * 4 + j, c = idx >> 3, ng = idx & 7;
                gload16(W2b + (size_t)(ng * 64 + lane) * 4096 + (t + 1) * 64 + c * 16,
                        smem + nb + c * 8192 + ng * 1024);
            }
        }
        const char* hb;
        int rstride, koffb;
        if (t < 32)      { hb = doutb; rstride = 2048; koffb = t * 64; }
        else if (t < 48) { hb = srcb;  rstride = 2048; koffb = (t - 32) * 64; }
        else             { hb = wsOb;  rstride = 1024; koffb = (t - 48) * 64; }
        const uint32_t B0 = (uint32_t)(t & 1) * 32768u;
        bf16x8 a[4];
#pragma unroll
        for (int i = 0; i < 4; ++i)
            a[i] = *(const bf16x8*)(hb + (size_t)(mb * 64 + i * 16 + l16) * rstride +
                                    koffb + quad * 16);
#pragma unroll
        for (int nt = 0; nt < 4; ++nt) {
            bf16x8 b = *(bf16x8*)(smem + B0 + quad * 8192 + (w * 64 + nt * 16 + l16) * 16);
#pragma unroll
            for (int i = 0; i < 4; ++i) acc[i][nt] = MFMA16(a[i], b, acc[i][nt]);
        }
        __syncthreads();  // drains this iter's prefetch; next buffer ready
    }

    // ---- epilogue: bias + residual(x1) + LN2 over full 512-col rows ----
#pragma unroll
    for (int nt = 0; nt < 4; ++nt) {
        int col = w * 64 + nt * 16 + l16;
        float bb = b2[col];
#pragma unroll
        for (int i = 0; i < 4; ++i)
#pragma unroll
            for (int r = 0; r < 4; ++r) {
                int row = mb * 64 + i * 16 + quad * 4 + r;
                float x1v = (float)*(const bf16*)(srcb + (size_t)row * 2048 + 1024 + col * 2);
                acc[i][nt][r] += bb + x1v;
            }
    }
    // per-(row) partials over this wave's 64 cols (sum nt, then 16-lane shfl)
    float ps[4][4], ps2[4][4];
#pragma unroll
    for (int i = 0; i < 4; ++i)
#pragma unroll
        for (int r = 0; r < 4; ++r) {
            float s = 0.f, s2 = 0.f;
#pragma unroll
            for (int nt = 0; nt < 4; ++nt) {
                float v = acc[i][nt][r];
                s += v;
                s2 += v * v;
            }
#pragma unroll
            for (int sft = 1; sft < 16; sft <<= 1) {
                s += __shfl_xor(s, sft, 64);
                s2 += __shfl_xor(s2, sft, 64);
            }
            ps[i][r] = s;
            ps2[i][r] = s2;
        }
    // cross-wave reduce via LDS scratch (dead buf0): [64 rows][8 w][2 f32]
    if (l16 == 0) {
#pragma unroll
        for (int i = 0; i < 4; ++i)
#pragma unroll
            for (int r = 0; r < 4; ++r) {
                int row_l = i * 16 + quad * 4 + r;
                *(float*)(smem + (uint32_t)(row_l * 64 + w * 8)) = ps[i][r];
                *(float*)(smem + (uint32_t)(row_l * 64 + w * 8 + 4)) = ps2[i][r];
            }
    }
    __syncthreads();
#pragma unroll
    for (int i = 0; i < 4; ++i)
#pragma unroll
        for (int r = 0; r < 4; ++r) {
            int row_l = i * 16 + quad * 4 + r;
            float S = 0.f, S2 = 0.f;
#pragma unroll
            for (int ww = 0; ww < 8; ++ww) {
                S  += *(const float*)(smem + (uint32_t)(row_l * 64 + ww * 8));
                S2 += *(const float*)(smem + (uint32_t)(row_l * 64 + ww * 8 + 4));
            }
            float mu = S * (1.0f / 512.0f);
            float var = S2 * (1.0f / 512.0f) - mu * mu;
            float rstd = rsqrtf(var + 1e-5f);
            size_t row = (size_t)(mb * 64 + row_l);
#pragma unroll
            for (int nt = 0; nt < 4; ++nt) {
                int col = w * 64 + nt * 16 + l16;
                *(float*)(doutb + row * 2048 + col * 4) =
                    (acc[i][nt][r] - mu) * rstd * g2[col] + be2[col];
            }
        }
}

extern "C" void kernel_launch(void* const* d_in, const int* in_sizes, int n_in,
                              void* d_out, int out_size, void* d_ws, size_t ws_size,
                              hipStream_t stream) {
    (void)in_sizes; (void)n_in; (void)out_size; (void)ws_size;
    float* src = (float*)d_in[0];
    const float* ipw = (const float*)d_in[1];
    const float* ipb = (const float*)d_in[2];
    const float* ow  = (const float*)d_in[3];
    const float* ob  = (const float*)d_in[4];
    const float* g1  = (const float*)d_in[5];
    const float* be1 = (const float*)d_in[6];
    const float* w1  = (const float*)d_in[7];
    const float* b1  = (const float*)d_in[8];
    const float* w2  = (const float*)d_in[9];
    const float* b2  = (const float*)d_in[10];
    const float* g2  = (const float*)d_in[11];
    const float* be2 = (const float*)d_in[12];
    bf16* ws = (bf16*)d_ws;
    char* srcb = (char*)src;
    char* doutb = (char*)d_out;
    char* qOb = (char*)d_ws + 6291456;  // 33.5 MB q/O/h-tail region

    wcvt_kernel<<<3072, 256, 0, stream>>>(ipw, ow, w1, w2, ws);
    xcvt_kernel<<<8192, 256, 0, stream>>>(src);

    hipFuncSetAttribute((const void*)qkv_kernel, hipFuncAttributeMaxDynamicSharedMemorySize, 32768);
    hipFuncSetAttribute((const void*)attn_kernel, hipFuncAttributeMaxDynamicSharedMemorySize, 32768);
    hipFuncSetAttribute((const void*)outproj_kernel, hipFuncAttributeMaxDynamicSharedMemorySize, 65536);
    hipFuncSetAttribute((const void*)ff1_kernel, hipFuncAttributeMaxDynamicSharedMemorySize, 32768);
    hipFuncSetAttribute((const void*)ff2_kernel, hipFuncAttributeMaxDynamicSharedMemorySize, 65536);

    qkv_kernel<<<dim3(256, 12), 256, 32768, stream>>>(srcb, ws, ipb, qOb, doutb);
    attn_kernel<<<2048, 512, 32768, stream>>>(qOb, doutb);
    outproj_kernel<<<512, 256, 65536, stream>>>(srcb, qOb, ws + 786432, ob, g1, be1);
    ff1_kernel<<<dim3(256, 8), 512, 32768, stream>>>(srcb, ws + 1048576, b1, doutb, qOb);
    ff2_kernel<<<512, 512, 65536, stream>>>(doutb, srcb, qOb, ws + 2097152, b2, g2, be2);
}

// Round 3
// 595.932 us; speedup vs baseline: 1.5178x; 1.5178x over previous
//
#include <hip/hip_runtime.h>
#include <hip/hip_bf16.h>
#include <math.h>

typedef __bf16 bf16;
typedef bf16 bf16x8 __attribute__((ext_vector_type(8)));
typedef bf16 bf16x4 __attribute__((ext_vector_type(4)));
typedef float f32x4 __attribute__((ext_vector_type(4)));

#define MFMA16(a, b, c) __builtin_amdgcn_mfma_f32_16x16x32_bf16(a, b, c, 0, 0, 0)

// XOR-swizzle on 16B chunks within a row: breaks power-of-2 row-stride bank aliasing.
__device__ __forceinline__ uint32_t swz(uint32_t base, uint32_t row, uint32_t rs, uint32_t cb) {
    return base + row * rs + (((cb >> 4) ^ (row & 7u)) << 4) + (cb & 15u);
}

// async global->LDS, 16B per lane. LDS dest = wave-uniform base + lane*16 (linear).
__device__ __forceinline__ void gload16(const void* g, void* l) {
    __builtin_amdgcn_global_load_lds((const __attribute__((address_space(1))) void*)g,
                                     (__attribute__((address_space(3))) void*)l, 16, 0, 0);
}

// Scratch map (row r = one of 32768 tokens):
//  src  slice r*2048B: [0,1024)=x_bf16 (xcvt; dead after outproj) -> h[1024:1536]
//                      [1024,2048)=x1 bf16 (outproj; read ff1, ff2-residual)
//  dout slice r*2048B: [0,1024)=k, [1024,2048)=v (qkv; dead after attn)
//                      -> h[0:1024] (ff1) -> final f32 out row (ff2, after h consumed)
//  ws: [0,6.3MB)=bf16 weights; [6.3,39.8MB) r*1024B: q (qkv) -> O (attn, same
//      block/cols) -> h[1536:2048] (ff1)
// Weight region layout (bf16 elems): Wqkv [0,786432) row-major [1536][512];
//  Wout [786432,1048576) row-major [512][512];
//  W1' [1048576,2097152) TILED: unit u (8 elems): tile=u>>11 (=cb*16+t), c=(u>>9)&3,
//      nn=u&511 -> W1[n=(tile>>4)*512+nn][k=(tile&15)*32+c*8+e]  (LDS image)
//  W2' [2097152,3145728) TILED: t=u>>11, c, nn -> W2[nn][t*32+c*8+e]

// ---------- weights f32 -> bf16 (+ k-tile-major repack of W1/W2) ----------
__global__ void wcvt_kernel(const float* __restrict__ w0, const float* __restrict__ w1o,
                            const float* __restrict__ w1f, const float* __restrict__ w2f,
                            bf16* __restrict__ o) {
    int i = blockIdx.x * blockDim.x + threadIdx.x;  // one 8-elem unit
    const float* s;
    int soff, doff;
    if (i < 98304)        { int e = i * 8; s = w0; soff = e; doff = e; }
    else if (i < 131072)  { int e = (i - 98304) * 8; s = w1o; soff = e; doff = 786432 + e; }
    else if (i < 262144)  {
        int u = i - 131072;
        int tile = u >> 11, c = (u >> 9) & 3, nn = u & 511;
        int n = (tile >> 4) * 512 + nn;
        int k = (tile & 15) * 32 + c * 8;
        s = w1f; soff = n * 512 + k; doff = 1048576 + u * 8;
    } else {
        int u = i - 262144;
        int t = u >> 11, c = (u >> 9) & 3, nn = u & 511;
        int k = t * 32 + c * 8;
        s = w2f; soff = nn * 2048 + k; doff = 2097152 + u * 8;
    }
    float4 v0 = *(const float4*)(s + soff);
    float4 v1 = *(const float4*)(s + soff + 4);
    bf16x8 h = { (bf16)v0.x, (bf16)v0.y, (bf16)v0.z, (bf16)v0.w,
                 (bf16)v1.x, (bf16)v1.y, (bf16)v1.z, (bf16)v1.w };
    *(bf16x8*)(o + doff) = h;
}

// ---------- src f32 -> bf16 in place (row-aligned slot; wave per row) ----------
__global__ void xcvt_kernel(float* __restrict__ src) {
    int row = blockIdx.x * 4 + (threadIdx.x >> 6);
    int l = threadIdx.x & 63;
    float* rp = src + (size_t)row * 512 + l * 8;
    float4 v0 = *(const float4*)rp;
    float4 v1 = *(const float4*)(rp + 4);
    asm volatile("s_waitcnt vmcnt(0)" ::: "memory");  // all wave reads before any write
    bf16x8 h = { (bf16)v0.x, (bf16)v0.y, (bf16)v0.z, (bf16)v0.w,
                 (bf16)v1.x, (bf16)v1.y, (bf16)v1.z, (bf16)v1.w };
    *(bf16x8*)((bf16*)(src + (size_t)row * 512) + l * 8) = h;
}

// ---------- qkv GEMM: M=32768 N=1536 K=512, 128x128 tiles ----------
extern "C" __global__ __launch_bounds__(256, 3)
void qkv_kernel(const char* __restrict__ xb, const bf16* __restrict__ Wqkv,
                const float* __restrict__ bqkv, char* __restrict__ qOb,
                char* __restrict__ kvb) {
    extern __shared__ char smem[];
    const int tid = threadIdx.x;
    const int wid = tid >> 6, lane = tid & 63, l16 = lane & 15, quad = lane >> 4;
    const int wm = wid >> 1, wn = wid & 1;
    const int rb = blockIdx.x, cb = blockIdx.y;
    f32x4 acc[4][4];
#pragma unroll
    for (int i = 0; i < 4; ++i)
#pragma unroll
        for (int nt = 0; nt < 4; ++nt) acc[i][nt] = (f32x4){0.f, 0.f, 0.f, 0.f};

#pragma unroll 1
    for (int kstep = 0; kstep < 8; ++kstep) {
        // stage B tile 128x64 bf16 -> LDS (swizzled, rs=128B)
        {
            int lr = tid >> 1, half = tid & 1;
            const char* g = (const char*)(Wqkv + (size_t)(cb * 128 + lr) * 512 + kstep * 64 + half * 32);
#pragma unroll
            for (int c = 0; c < 4; ++c) {
                bf16x8 v = *(const bf16x8*)(g + c * 16);
                *(bf16x8*)(smem + swz(0, lr, 128, half * 64 + c * 16)) = v;
            }
        }
        __syncthreads();
#pragma unroll
        for (int k16 = 0; k16 < 2; ++k16) {
            bf16x8 a[4];
#pragma unroll
            for (int i = 0; i < 4; ++i) {
                int row = rb * 128 + wm * 64 + i * 16 + l16;
                a[i] = *(const bf16x8*)(xb + (size_t)row * 2048 + (kstep * 64 + k16 * 32 + quad * 8) * 2);
            }
#pragma unroll
            for (int nt = 0; nt < 4; ++nt) {
                bf16x8 b = *(bf16x8*)(smem + swz(0, wn * 64 + nt * 16 + l16, 128, k16 * 64 + quad * 16));
#pragma unroll
                for (int i = 0; i < 4; ++i) acc[i][nt] = MFMA16(a[i], b, acc[i][nt]);
            }
        }
        __syncthreads();  // after last iter: B region dead -> transpose scratch
    }
    // ---- bias + C->rowmajor transpose through wave-private LDS (8KB/wave) ----
    const uint32_t wb = (uint32_t)wid * 8192;  // 64 rows x 128B
#pragma unroll
    for (int nt = 0; nt < 4; ++nt) {
        float bias = bqkv[cb * 128 + wn * 64 + nt * 16 + l16];
#pragma unroll
        for (int i = 0; i < 4; ++i)
#pragma unroll
            for (int r = 0; r < 4; ++r)
                *(bf16*)(smem + swz(wb, i * 16 + quad * 4 + r, 128, (nt * 16 + l16) * 2)) =
                    (bf16)(acc[i][nt][r] + bias);
    }
    asm volatile("s_waitcnt lgkmcnt(0)" ::: "memory");
    const int region = cb >> 2;  // 0=q, 1=k, 2=v (uniform per block)
#pragma unroll
    for (int c = 0; c < 8; ++c) {
        int lr = c * 8 + (lane >> 3), ch = lane & 7;
        bf16x8 v = *(bf16x8*)(smem + swz(wb, lr, 128, ch * 16));
        int row_g = rb * 128 + wm * 64 + lr;
        int colb = (cb * 128 + wn * 64) * 2 + ch * 16;  // byte col in 1536*2 space
        if (region == 0)      *(bf16x8*)(qOb + (size_t)row_g * 1024 + colb) = v;
        else if (region == 1) *(bf16x8*)(kvb + (size_t)row_g * 2048 + (colb - 1024)) = v;
        else                  *(bf16x8*)(kvb + (size_t)row_g * 2048 + 1024 + (colb - 2048)) = v;
    }
}

// ---------- attention: one block per (window, head) ----------
#define AVT 0u       // vT 64x128 bf16 rs=256B (16KB)
#define ASCR 16384u  // 8 waves x 2KB transpose scratch
extern "C" __global__ __launch_bounds__(512, 4)
void attn_kernel(char* __restrict__ qOb, const char* __restrict__ kvb) {
    extern __shared__ char smem[];
    const int tid = threadIdx.x;
    const int wid = tid >> 6, lane = tid & 63, l16 = lane & 15, quad = lane >> 4;
    const int win = blockIdx.x >> 3, head = blockIdx.x & 7;
    const size_t wrow0 = (size_t)win * 128;
    f32x4 zero4 = { 0.f, 0.f, 0.f, 0.f };

    // stage vT[dim][key] from v rows
    {
        int key = tid >> 2, d0 = (tid & 3) * 16;
        const char* vs = kvb + (wrow0 + key) * 2048 + 1024 + head * 128 + d0 * 2;
#pragma unroll
        for (int j = 0; j < 2; ++j) {
            bf16x8 v = *(const bf16x8*)(vs + j * 16);
#pragma unroll
            for (int e = 0; e < 8; ++e)
                *(bf16*)(smem + swz(AVT, d0 + j * 8 + e, 256, key * 2)) = v[e];
        }
    }
    __syncthreads();  // only barrier in this kernel

    // q fragments (A layout, direct from global)
    bf16x8 qf[2];
#pragma unroll
    for (int ks = 0; ks < 2; ++ks)
        qf[ks] = *(const bf16x8*)(qOb + (wrow0 + wid * 16 + l16) * 1024 + head * 128 + ks * 64 + quad * 16);

    // scores (k B-frags direct from global)
    f32x4 sa[8];
#pragma unroll
    for (int nt = 0; nt < 8; ++nt) sa[nt] = zero4;
#pragma unroll
    for (int nt = 0; nt < 8; ++nt)
#pragma unroll
        for (int ks = 0; ks < 2; ++ks) {
            bf16x8 kb = *(const bf16x8*)(kvb + (wrow0 + nt * 16 + l16) * 2048 + head * 128 + ks * 64 + quad * 16);
            sa[nt] = MFMA16(qf[ks], kb, sa[nt]);
        }
#pragma unroll
    for (int nt = 0; nt < 8; ++nt) sa[nt] *= 0.125f;
#pragma unroll
    for (int r = 0; r < 4; ++r) {
        float m = sa[0][r];
#pragma unroll
        for (int nt = 1; nt < 8; ++nt) m = fmaxf(m, sa[nt][r]);
#pragma unroll
        for (int sft = 1; sft < 16; sft <<= 1) m = fmaxf(m, __shfl_xor(m, sft, 64));
        float s = 0.f;
#pragma unroll
        for (int nt = 0; nt < 8; ++nt) {
            float e = __expf(sa[nt][r] - m);
            sa[nt][r] = e;
            s += e;
        }
#pragma unroll
        for (int sft = 1; sft < 16; sft <<= 1) s += __shfl_xor(s, sft, 64);
        float inv = 1.0f / s;
#pragma unroll
        for (int nt = 0; nt < 8; ++nt) sa[nt][r] *= inv;
    }

    // P C->A transpose through wave-private scratch
    const uint32_t sb = ASCR + (uint32_t)wid * 2048;
    bf16x8 pf[4];
#pragma unroll
    for (int hf = 0; hf < 2; ++hf) {
#pragma unroll
        for (int nt = 0; nt < 4; ++nt)
#pragma unroll
            for (int r = 0; r < 4; ++r)
                *(bf16*)(smem + swz(sb, quad * 4 + r, 128, (nt * 16 + l16) * 2)) = (bf16)sa[hf * 4 + nt][r];
        asm volatile("s_waitcnt lgkmcnt(0)" ::: "memory");
#pragma unroll
        for (int ks = 0; ks < 2; ++ks)
            pf[hf * 2 + ks] = *(bf16x8*)(smem + swz(sb, l16, 128, ks * 64 + quad * 16));
        asm volatile("s_waitcnt lgkmcnt(0)" ::: "memory");
    }

    // O = P @ V
    f32x4 ov[4];
#pragma unroll
    for (int nt = 0; nt < 4; ++nt) {
        ov[nt] = zero4;
#pragma unroll
        for (int ks = 0; ks < 4; ++ks) {
            bf16x8 vb = *(bf16x8*)(smem + swz(AVT, nt * 16 + l16, 256, ks * 64 + quad * 16));
            ov[nt] = MFMA16(pf[ks], vb, ov[nt]);
        }
    }
    // O store via transpose: two 32-col halves through 2KB wave scratch (rs=128)
#pragma unroll
    for (int hf = 0; hf < 2; ++hf) {
#pragma unroll
        for (int nt = 0; nt < 2; ++nt)
#pragma unroll
            for (int r = 0; r < 4; ++r)
                *(bf16*)(smem + swz(sb, quad * 4 + r, 128, (nt * 16 + l16) * 2)) = (bf16)ov[hf * 2 + nt][r];
        asm volatile("s_waitcnt lgkmcnt(0)" ::: "memory");
        {
            int row = lane >> 2, ch = lane & 3;
            bf16x8 v = *(bf16x8*)(smem + swz(sb, row, 128, ch * 16));
            *(bf16x8*)(qOb + (wrow0 + wid * 16 + row) * 1024 + head * 128 + hf * 64 + ch * 16) = v;
        }
        asm volatile("s_waitcnt lgkmcnt(0)" ::: "memory");
    }
}

// ---------- out-proj + residual + LN1: M=32768 N=512 K=512 ----------
extern "C" __global__ __launch_bounds__(256, 2)
void outproj_kernel(char* __restrict__ srcb, const char* __restrict__ qOb,
                    const bf16* __restrict__ Wout, const float* __restrict__ bout,
                    const float* __restrict__ g1, const float* __restrict__ be1) {
    extern __shared__ char smem[];
    const int tid = threadIdx.x;
    const int wid = tid >> 6, lane = tid & 63, l16 = lane & 15, quad = lane >> 4;
    const int mb = blockIdx.x;
    f32x4 acc[32];
#pragma unroll
    for (int nt = 0; nt < 32; ++nt) acc[nt] = (f32x4){0.f, 0.f, 0.f, 0.f};

#pragma unroll 1
    for (int kstep = 0; kstep < 8; ++kstep) {
        {
            int n0 = tid * 2;
#pragma unroll
            for (int rr = 0; rr < 2; ++rr) {
                int n = n0 + rr;
                const char* g = (const char*)(Wout + (size_t)n * 512 + kstep * 64);
#pragma unroll
                for (int c = 0; c < 8; ++c) {
                    bf16x8 v = *(const bf16x8*)(g + c * 16);
                    *(bf16x8*)(smem + swz(0, n, 128, c * 16)) = v;
                }
            }
        }
        __syncthreads();
#pragma unroll
        for (int k16 = 0; k16 < 2; ++k16) {
            bf16x8 a = *(const bf16x8*)(qOb + (size_t)(mb * 64 + wid * 16 + l16) * 1024 +
                                        (kstep * 64 + k16 * 32 + quad * 8) * 2);
#pragma unroll
            for (int nt = 0; nt < 32; ++nt) {
                bf16x8 b = *(bf16x8*)(smem + swz(0, nt * 16 + l16, 128, k16 * 64 + quad * 16));
                acc[nt] = MFMA16(a, b, acc[nt]);
            }
        }
        __syncthreads();  // after last iter: B region dead -> transpose scratch
    }
    // bias + residual (bf16 x) + LN1 (wave owns full row)
#pragma unroll
    for (int nt = 0; nt < 32; ++nt) {
        int col = nt * 16 + l16;
        float bb = bout[col];
#pragma unroll
        for (int r = 0; r < 4; ++r) {
            int row = mb * 64 + wid * 16 + quad * 4 + r;
            float xv = (float)*(const bf16*)(srcb + (size_t)row * 2048 + col * 2);
            acc[nt][r] += bb + xv;
        }
    }
    const uint32_t wb = (uint32_t)wid * 16384;  // 16 rows x 1024B
#pragma unroll
    for (int r = 0; r < 4; ++r) {
        float s = 0.f, s2 = 0.f;
#pragma unroll
        for (int nt = 0; nt < 32; ++nt) {
            float v = acc[nt][r];
            s += v;
            s2 += v * v;
        }
#pragma unroll
        for (int sft = 1; sft < 16; sft <<= 1) {
            s += __shfl_xor(s, sft, 64);
            s2 += __shfl_xor(s2, sft, 64);
        }
        float mu = s * (1.0f / 512.0f);
        float var = s2 * (1.0f / 512.0f) - mu * mu;
        float rstd = rsqrtf(var + 1e-5f);
#pragma unroll
        for (int nt = 0; nt < 32; ++nt) {
            int col = nt * 16 + l16;
            float v = (acc[nt][r] - mu) * rstd * g1[col] + be1[col];
            *(bf16*)(smem + swz(wb, quad * 4 + r, 1024, col * 2)) = (bf16)v;
        }
    }
    asm volatile("s_waitcnt lgkmcnt(0)" ::: "memory");
#pragma unroll
    for (int t = 0; t < 16; ++t) {
        int row = (t >> 2) * 4 + (lane >> 4);
        int ch = (t & 3) * 16 + l16;
        bf16x8 v = *(bf16x8*)(smem + swz(wb, row, 1024, ch * 16));
        *(bf16x8*)(srcb + (size_t)(mb * 64 + wid * 16 + row) * 2048 + 1024 + ch * 16) = v;
    }
}

// ---------- FF1 v3: M=32768 N=2048 K=512; 128x512 tile, grid (256,4) ----------
// 8 waves (2x4), wave tile 64x128; BK=32, 16 iters; A+B dbuf via gload_lds.
// B staged COALESCED from k-tile-major W1' (LDS image == global image).
// LDS: A 2x8KB at 0; B 2x32KB at 16384. Total 80KB, 1 block/CU.
extern "C" __global__ __launch_bounds__(512, 2)
void ff1_kernel(char* __restrict__ srcb, const char* __restrict__ W1p,
                const float* __restrict__ b1, char* __restrict__ doutb,
                char* __restrict__ wsOb) {
    extern __shared__ char smem[];
    const int tid = threadIdx.x;
    const int w = tid >> 6, lane = tid & 63, l16 = lane & 15, quad = lane >> 4;
    const int wm = w >> 2, wn = w & 3;
    const int mb = blockIdx.x, cb = blockIdx.y;

    f32x4 acc[4][8];
#pragma unroll
    for (int i = 0; i < 4; ++i)
#pragma unroll
        for (int nt = 0; nt < 8; ++nt) acc[i][nt] = (f32x4){0.f, 0.f, 0.f, 0.f};

    // ---- stage tile t into buffer buf ----
#define FF1_STAGE(buf, t)                                                              \
    {                                                                                  \
        int ca = w >> 1, rg = w & 1; /* A: 8 wave-issues (gathered rows) */            \
        gload16(srcb + (size_t)(mb * 128 + rg * 64 + lane) * 2048 + 1024 + (t) * 64 + ca * 16, \
                smem + (uint32_t)(buf) * 8192u + ca * 2048 + rg * 1024);               \
        _Pragma("unroll")                                                              \
        for (int j = 0; j < 4; ++j) { /* B: 32 wave-issues, contiguous 1KB each */     \
            int idx = w * 4 + j, c = idx >> 3, ng = idx & 7;                           \
            gload16(W1p + (size_t)(cb * 16 + (t)) * 32768 + c * 8192 + ng * 1024 + lane * 16, \
                    smem + 16384u + (uint32_t)(buf) * 32768u + (uint32_t)c * 8192 + (uint32_t)ng * 1024); \
        }                                                                              \
    }

    FF1_STAGE(0, 0);
    __syncthreads();

#pragma unroll 1
    for (int t = 0; t < 16; ++t) {
        if (t < 15) FF1_STAGE((t + 1) & 1, t + 1);
        const uint32_t A0 = (uint32_t)(t & 1) * 8192u;
        const uint32_t B0 = 16384u + (uint32_t)(t & 1) * 32768u;
        bf16x8 a[4];
#pragma unroll
        for (int i = 0; i < 4; ++i)
            a[i] = *(const bf16x8*)(smem + A0 + quad * 2048 + (wm * 64 + i * 16 + l16) * 16);
#pragma unroll
        for (int nt = 0; nt < 8; ++nt) {
            bf16x8 b = *(const bf16x8*)(smem + B0 + quad * 8192 + (wn * 128 + nt * 16 + l16) * 16);
#pragma unroll
            for (int i = 0; i < 4; ++i) acc[i][nt] = MFMA16(a[i], b, acc[i][nt]);
        }
        __syncthreads();  // drains this iter's prefetch; next buffer ready
    }
#undef FF1_STAGE

    // epilogue: bias+relu; per-i 16x128-col transpose through 4KB wave scratch
    const uint32_t sb = 16384u + (uint32_t)w * 4096u;  // dead B-buf0 region
#pragma unroll
    for (int i = 0; i < 4; ++i) {
#pragma unroll
        for (int nt = 0; nt < 8; ++nt) {
            float bb = b1[cb * 512 + wn * 128 + nt * 16 + l16];
#pragma unroll
            for (int r = 0; r < 4; ++r)
                *(bf16*)(smem + swz(sb, quad * 4 + r, 256, (nt * 16 + l16) * 2)) =
                    (bf16)fmaxf(acc[i][nt][r] + bb, 0.0f);
        }
        asm volatile("s_waitcnt lgkmcnt(0)" ::: "memory");
#pragma unroll
        for (int j = 0; j < 4; ++j) {
            int uu = j * 64 + lane;  // 0..255: 16 rows x 16 chunks
            int row = uu >> 4, ch = uu & 15;
            bf16x8 v = *(bf16x8*)(smem + swz(sb, row, 256, ch * 16));
            size_t row_g = (size_t)(mb * 128 + wm * 64 + i * 16 + row);
            int nb2 = wn * 256 + ch * 16;  // byte within this cb's 1024B col-slice
            if (cb < 2)       *(bf16x8*)(doutb + row_g * 2048 + cb * 1024 + nb2) = v;
            else if (cb == 2) *(bf16x8*)(srcb + row_g * 2048 + nb2) = v;
            else              *(bf16x8*)(wsOb + row_g * 1024 + nb2) = v;
        }
        asm volatile("s_waitcnt lgkmcnt(0)" ::: "memory");
    }
}

// ---------- FF2 v5 + residual + LN2: M=32768 N=512 K=2048 -> f32 out ----------
// 128x512 tile (grid 256), 8 waves (2x4), wave tile 64x128; BK=32, 64 iters.
// B staged COALESCED from k-tile-major W2'; A (h, 3-region) staged gathered.
// LDS: A 2x8KB at 0; B 2x32KB at 16384. Total 80KB, 1 block/CU.
extern "C" __global__ __launch_bounds__(512, 2)
void ff2_kernel(char* __restrict__ doutb, const char* __restrict__ srcb,
                const char* __restrict__ wsOb, const char* __restrict__ W2p,
                const float* __restrict__ b2, const float* __restrict__ g2,
                const float* __restrict__ be2) {
    extern __shared__ char smem[];
    const int tid = threadIdx.x;
    const int w = tid >> 6, lane = tid & 63, l16 = lane & 15, quad = lane >> 4;
    const int wm = w >> 2, wn = w & 3;
    const int mb = blockIdx.x;

    f32x4 acc[4][8];
#pragma unroll
    for (int i = 0; i < 4; ++i)
#pragma unroll
        for (int nt = 0; nt < 8; ++nt) acc[i][nt] = (f32x4){0.f, 0.f, 0.f, 0.f};

#define FF2_STAGE(buf, t)                                                              \
    {                                                                                  \
        const char* hb; int rstride, koffb;                                            \
        if ((t) < 32)      { hb = doutb; rstride = 2048; koffb = (t) * 64; }           \
        else if ((t) < 48) { hb = srcb;  rstride = 2048; koffb = ((t) - 32) * 64; }    \
        else               { hb = wsOb;  rstride = 1024; koffb = ((t) - 48) * 64; }    \
        int ca = w >> 1, rg = w & 1; /* A: 8 wave-issues (gathered h rows) */          \
        gload16(hb + (size_t)(mb * 128 + rg * 64 + lane) * rstride + koffb + ca * 16,  \
                smem + (uint32_t)(buf) * 8192u + ca * 2048 + rg * 1024);               \
        _Pragma("unroll")                                                              \
        for (int j = 0; j < 4; ++j) { /* B: 32 wave-issues, contiguous 1KB each */     \
            int idx = w * 4 + j, c = idx >> 3, ng = idx & 7;                           \
            gload16(W2p + (size_t)(t) * 32768 + c * 8192 + ng * 1024 + lane * 16,      \
                    smem + 16384u + (uint32_t)(buf) * 32768u + (uint32_t)c * 8192 + (uint32_t)ng * 1024); \
        }                                                                              \
    }

    FF2_STAGE(0, 0);
    __syncthreads();

#pragma unroll 1
    for (int t = 0; t < 64; ++t) {
        if (t < 63) FF2_STAGE((t + 1) & 1, t + 1);
        const uint32_t A0 = (uint32_t)(t & 1) * 8192u;
        const uint32_t B0 = 16384u + (uint32_t)(t & 1) * 32768u;
        bf16x8 a[4];
#pragma unroll
        for (int i = 0; i < 4; ++i)
            a[i] = *(const bf16x8*)(smem + A0 + quad * 2048 + (wm * 64 + i * 16 + l16) * 16);
#pragma unroll
        for (int nt = 0; nt < 8; ++nt) {
            bf16x8 b = *(const bf16x8*)(smem + B0 + quad * 8192 + (wn * 128 + nt * 16 + l16) * 16);
#pragma unroll
            for (int i = 0; i < 4; ++i) acc[i][nt] = MFMA16(a[i], b, acc[i][nt]);
        }
        __syncthreads();  // drains this iter's prefetch; next buffer ready
    }
#undef FF2_STAGE

    // ---- epilogue: bias + residual(x1) + LN2 over full 512-col rows ----
#pragma unroll
    for (int nt = 0; nt < 8; ++nt) {
        int col = wn * 128 + nt * 16 + l16;
        float bb = b2[col];
#pragma unroll
        for (int i = 0; i < 4; ++i)
#pragma unroll
            for (int r = 0; r < 4; ++r) {
                int row = mb * 128 + wm * 64 + i * 16 + quad * 4 + r;
                float x1v = (float)*(const bf16*)(srcb + (size_t)row * 2048 + 1024 + col * 2);
                acc[i][nt][r] += bb + x1v;
            }
    }
    // per-(row, wave) partials over this wave's 128 cols
    float ps[4][4], ps2[4][4];
#pragma unroll
    for (int i = 0; i < 4; ++i)
#pragma unroll
        for (int r = 0; r < 4; ++r) {
            float s = 0.f, s2 = 0.f;
#pragma unroll
            for (int nt = 0; nt < 8; ++nt) {
                float v = acc[i][nt][r];
                s += v;
                s2 += v * v;
            }
#pragma unroll
            for (int sft = 1; sft < 16; sft <<= 1) {
                s += __shfl_xor(s, sft, 64);
                s2 += __shfl_xor(s2, sft, 64);
            }
            ps[i][r] = s;
            ps2[i][r] = s2;
        }
    // cross-wave reduce via LDS scratch (A-buf region dead): [128 rows][4 wn][2 f32]
    if (l16 == 0) {
#pragma unroll
        for (int i = 0; i < 4; ++i)
#pragma unroll
            for (int r = 0; r < 4; ++r) {
                int row_l = wm * 64 + i * 16 + quad * 4 + r;
                *(float*)(smem + row_l * 32 + wn * 8) = ps[i][r];
                *(float*)(smem + row_l * 32 + wn * 8 + 4) = ps2[i][r];
            }
    }
    __syncthreads();
#pragma unroll
    for (int i = 0; i < 4; ++i)
#pragma unroll
        for (int r = 0; r < 4; ++r) {
            int row_l = wm * 64 + i * 16 + quad * 4 + r;
            float S = 0.f, S2 = 0.f;
#pragma unroll
            for (int w4 = 0; w4 < 4; ++w4) {
                S += *(const float*)(smem + row_l * 32 + w4 * 8);
                S2 += *(const float*)(smem + row_l * 32 + w4 * 8 + 4);
            }
            float mu = S * (1.0f / 512.0f);
            float var = S2 * (1.0f / 512.0f) - mu * mu;
            float rstd = rsqrtf(var + 1e-5f);
            size_t row = (size_t)(mb * 128 + row_l);
#pragma unroll
            for (int nt = 0; nt < 8; ++nt) {
                int col = wn * 128 + nt * 16 + l16;
                *(float*)(doutb + row * 2048 + col * 4) =
                    (acc[i][nt][r] - mu) * rstd * g2[col] + be2[col];
            }
        }
}

extern "C" void kernel_launch(void* const* d_in, const int* in_sizes, int n_in,
                              void* d_out, int out_size, void* d_ws, size_t ws_size,
                              hipStream_t stream) {
    (void)in_sizes; (void)n_in; (void)out_size; (void)ws_size;
    float* src = (float*)d_in[0];
    const float* ipw = (const float*)d_in[1];
    const float* ipb = (const float*)d_in[2];
    const float* ow  = (const float*)d_in[3];
    const float* ob  = (const float*)d_in[4];
    const float* g1  = (const float*)d_in[5];
    const float* be1 = (const float*)d_in[6];
    const float* w1  = (const float*)d_in[7];
    const float* b1  = (const float*)d_in[8];
    const float* w2  = (const float*)d_in[9];
    const float* b2  = (const float*)d_in[10];
    const float* g2  = (const float*)d_in[11];
    const float* be2 = (const float*)d_in[12];
    bf16* ws = (bf16*)d_ws;
    char* srcb = (char*)src;
    char* doutb = (char*)d_out;
    char* qOb = (char*)d_ws + 6291456;  // 33.5 MB q/O/h-tail region

    wcvt_kernel<<<1536, 256, 0, stream>>>(ipw, ow, w1, w2, ws);
    xcvt_kernel<<<8192, 256, 0, stream>>>(src);

    hipFuncSetAttribute((const void*)qkv_kernel, hipFuncAttributeMaxDynamicSharedMemorySize, 32768);
    hipFuncSetAttribute((const void*)attn_kernel, hipFuncAttributeMaxDynamicSharedMemorySize, 32768);
    hipFuncSetAttribute((const void*)outproj_kernel, hipFuncAttributeMaxDynamicSharedMemorySize, 65536);
    hipFuncSetAttribute((const void*)ff1_kernel, hipFuncAttributeMaxDynamicSharedMemorySize, 81920);
    hipFuncSetAttribute((const void*)ff2_kernel, hipFuncAttributeMaxDynamicSharedMemorySize, 81920);

    qkv_kernel<<<dim3(256, 12), 256, 32768, stream>>>(srcb, ws, ipb, qOb, doutb);
    attn_kernel<<<2048, 512, 32768, stream>>>(qOb, doutb);
    outproj_kernel<<<512, 256, 65536, stream>>>(srcb, qOb, ws + 786432, ob, g1, be1);
    ff1_kernel<<<dim3(256, 4), 512, 81920, stream>>>(srcb, (const char*)(ws + 1048576), b1, doutb, qOb);
    ff2_kernel<<<256, 512, 81920, stream>>>(doutb, srcb, qOb, (const char*)(ws + 2097152), b2, g2, be2);
}

// Round 4
// 524.420 us; speedup vs baseline: 1.7248x; 1.1364x over previous
//
#include <hip/hip_runtime.h>
#include <hip/hip_bf16.h>
#include <math.h>

typedef __bf16 bf16;
typedef bf16 bf16x8 __attribute__((ext_vector_type(8)));
typedef bf16 bf16x4 __attribute__((ext_vector_type(4)));
typedef float f32x4 __attribute__((ext_vector_type(4)));

#define MFMA16(a, b, c) __builtin_amdgcn_mfma_f32_16x16x32_bf16(a, b, c, 0, 0, 0)

// XOR-swizzle on 16B chunks within a row: breaks power-of-2 row-stride bank aliasing.
__device__ __forceinline__ uint32_t swz(uint32_t base, uint32_t row, uint32_t rs, uint32_t cb) {
    return base + row * rs + (((cb >> 4) ^ (row & 7u)) << 4) + (cb & 15u);
}

// async global->LDS, 16B per lane. LDS dest = wave-uniform base + lane*16 (linear).
__device__ __forceinline__ void gload16(const void* g, void* l) {
    __builtin_amdgcn_global_load_lds((const __attribute__((address_space(1))) void*)g,
                                     (__attribute__((address_space(3))) void*)l, 16, 0, 0);
}

// Scratch map (row r = one of 32768 tokens):
//  src  slice r*2048B: [0,1024)=x_bf16 (xcvt; dead after outproj) -> h[1024:1536]
//                      [1024,2048)=x1 bf16 (outproj; read ff1, ff2-residual)
//  dout slice r*2048B: [0,1024)=k, [1024,2048)=v (qkv; dead after attn)
//                      -> h[0:1024] (ff1) -> final f32 out row (ff2, after h consumed)
//  ws: [0,6.3MB)=bf16 weights; [6.3,39.8MB) r*1024B: q (qkv) -> O (attn, same
//      block/cols) -> h[1536:2048] (ff1)
// Weight region layout (bf16 elems), ALL k-tile-major "LDS image" [tile][c][nn]:
//  unit u = 8 elems; within a region: tile=u>>11, c=(u>>9)&3, nn=u&511;
//  tile is 32KB = one K-step's B-panel; k = (tile%T_K)*32 + c*8, T_K = K/32.
//  Wqkv' [0,786432):        48 tiles; n=(tile>>4)*512+nn, k=(tile&15)*32+c*8
//  Wout' [786432,1048576):  16 tiles; n=nn, k=tile*32+c*8
//  W1'  [1048576,2097152): 128 tiles; n=(tile>>4)*512+nn, k=(tile&15)*32+c*8
//  W2'  [2097152,3145728):  64 tiles; n=nn, k=tile*32+c*8

// ---------- weights f32 -> bf16, k-tile-major repack ----------
__global__ void wcvt_kernel(const float* __restrict__ wqkv, const float* __restrict__ wout,
                            const float* __restrict__ w1f, const float* __restrict__ w2f,
                            bf16* __restrict__ o) {
    int i = blockIdx.x * blockDim.x + threadIdx.x;  // one 8-elem unit
    const float* s;
    int soff, doff;
    if (i < 98304) {  // Wqkv: [1536][512] -> 48 tiles
        int u = i;
        int tile = u >> 11, c = (u >> 9) & 3, nn = u & 511;
        int n = (tile >> 4) * 512 + nn;
        int k = (tile & 15) * 32 + c * 8;
        s = wqkv; soff = n * 512 + k; doff = u * 8;
    } else if (i < 131072) {  // Wout: [512][512] -> 16 tiles
        int u = i - 98304;
        int tile = u >> 11, c = (u >> 9) & 3, nn = u & 511;
        int k = tile * 32 + c * 8;
        s = wout; soff = nn * 512 + k; doff = 786432 + u * 8;
    } else if (i < 262144) {  // W1: [2048][512] -> 128 tiles
        int u = i - 131072;
        int tile = u >> 11, c = (u >> 9) & 3, nn = u & 511;
        int n = (tile >> 4) * 512 + nn;
        int k = (tile & 15) * 32 + c * 8;
        s = w1f; soff = n * 512 + k; doff = 1048576 + u * 8;
    } else {  // W2: [512][2048] -> 64 tiles
        int u = i - 262144;
        int t = u >> 11, c = (u >> 9) & 3, nn = u & 511;
        int k = t * 32 + c * 8;
        s = w2f; soff = nn * 2048 + k; doff = 2097152 + u * 8;
    }
    float4 v0 = *(const float4*)(s + soff);
    float4 v1 = *(const float4*)(s + soff + 4);
    bf16x8 h = { (bf16)v0.x, (bf16)v0.y, (bf16)v0.z, (bf16)v0.w,
                 (bf16)v1.x, (bf16)v1.y, (bf16)v1.z, (bf16)v1.w };
    *(bf16x8*)(o + doff) = h;
}

// ---------- src f32 -> bf16 in place (row-aligned slot; wave per row) ----------
__global__ void xcvt_kernel(float* __restrict__ src) {
    int row = blockIdx.x * 4 + (threadIdx.x >> 6);
    int l = threadIdx.x & 63;
    float* rp = src + (size_t)row * 512 + l * 8;
    float4 v0 = *(const float4*)rp;
    float4 v1 = *(const float4*)(rp + 4);
    asm volatile("s_waitcnt vmcnt(0)" ::: "memory");  // all wave reads before any write
    bf16x8 h = { (bf16)v0.x, (bf16)v0.y, (bf16)v0.z, (bf16)v0.w,
                 (bf16)v1.x, (bf16)v1.y, (bf16)v1.z, (bf16)v1.w };
    *(bf16x8*)((bf16*)(src + (size_t)row * 512) + l * 8) = h;
}

// ---------- qkv GEMM v2: M=32768 N=1536 K=512; 128x512 tile, grid (256,3) ----------
// 8 waves (2x4), wave tile 64x128; BK=32, 16 iters; A+B dbuf via gload_lds.
// B staged COALESCED from k-tile-major Wqkv'. Block's 512-col slice = one of q/k/v.
extern "C" __global__ __launch_bounds__(512, 2)
void qkv_kernel(const char* __restrict__ xb, const char* __restrict__ Wqkvp,
                const float* __restrict__ bqkv, char* __restrict__ qOb,
                char* __restrict__ kvb) {
    extern __shared__ char smem[];
    const int tid = threadIdx.x;
    const int w = tid >> 6, lane = tid & 63, l16 = lane & 15, quad = lane >> 4;
    const int wm = w >> 2, wn = w & 3;
    const int mb = blockIdx.x, cb = blockIdx.y;

    f32x4 acc[4][8];
#pragma unroll
    for (int i = 0; i < 4; ++i)
#pragma unroll
        for (int nt = 0; nt < 8; ++nt) acc[i][nt] = (f32x4){0.f, 0.f, 0.f, 0.f};

#define QKV_STAGE(buf, t)                                                              \
    {                                                                                  \
        int ca = w >> 1, rg = w & 1; /* A: 8 wave-issues (gathered x rows) */          \
        gload16(xb + (size_t)(mb * 128 + rg * 64 + lane) * 2048 + (t) * 64 + ca * 16,  \
                smem + (uint32_t)(buf) * 8192u + ca * 2048 + rg * 1024);               \
        _Pragma("unroll")                                                              \
        for (int j = 0; j < 4; ++j) { /* B: 32 wave-issues, contiguous 1KB each */     \
            int idx = w * 4 + j, c = idx >> 3, ng = idx & 7;                           \
            gload16(Wqkvp + (size_t)(cb * 16 + (t)) * 32768 + c * 8192 + ng * 1024 + lane * 16, \
                    smem + 16384u + (uint32_t)(buf) * 32768u + (uint32_t)c * 8192 + (uint32_t)ng * 1024); \
        }                                                                              \
    }

    QKV_STAGE(0, 0);
    __syncthreads();

#pragma unroll 1
    for (int t = 0; t < 16; ++t) {
        if (t < 15) QKV_STAGE((t + 1) & 1, t + 1);
        const uint32_t A0 = (uint32_t)(t & 1) * 8192u;
        const uint32_t B0 = 16384u + (uint32_t)(t & 1) * 32768u;
        bf16x8 a[4];
#pragma unroll
        for (int i = 0; i < 4; ++i)
            a[i] = *(const bf16x8*)(smem + A0 + quad * 2048 + (wm * 64 + i * 16 + l16) * 16);
#pragma unroll
        for (int nt = 0; nt < 8; ++nt) {
            bf16x8 b = *(const bf16x8*)(smem + B0 + quad * 8192 + (wn * 128 + nt * 16 + l16) * 16);
#pragma unroll
            for (int i = 0; i < 4; ++i) acc[i][nt] = MFMA16(a[i], b, acc[i][nt]);
        }
        __syncthreads();
    }
#undef QKV_STAGE

    // epilogue: bias; per-i 16x128 transpose through 4KB wave scratch (dead B-buf0)
    const uint32_t sb = 16384u + (uint32_t)w * 4096u;
#pragma unroll
    for (int i = 0; i < 4; ++i) {
#pragma unroll
        for (int nt = 0; nt < 8; ++nt) {
            float bb = bqkv[cb * 512 + wn * 128 + nt * 16 + l16];
#pragma unroll
            for (int r = 0; r < 4; ++r)
                *(bf16*)(smem + swz(sb, quad * 4 + r, 256, (nt * 16 + l16) * 2)) =
                    (bf16)(acc[i][nt][r] + bb);
        }
        asm volatile("s_waitcnt lgkmcnt(0)" ::: "memory");
#pragma unroll
        for (int j = 0; j < 4; ++j) {
            int uu = j * 64 + lane;  // 16 rows x 16 chunks
            int row = uu >> 4, ch = uu & 15;
            bf16x8 v = *(bf16x8*)(smem + swz(sb, row, 256, ch * 16));
            size_t row_g = (size_t)(mb * 128 + wm * 64 + i * 16 + row);
            int nb2 = wn * 256 + ch * 16;  // byte within this cb's 1024B col-slice
            if (cb == 0)      *(bf16x8*)(qOb + row_g * 1024 + nb2) = v;
            else if (cb == 1) *(bf16x8*)(kvb + row_g * 2048 + nb2) = v;
            else              *(bf16x8*)(kvb + row_g * 2048 + 1024 + nb2) = v;
        }
        asm volatile("s_waitcnt lgkmcnt(0)" ::: "memory");
    }
}

// ---------- attention: one block per (window, head) ----------
#define AVT 0u       // vT 64x128 bf16 rs=256B (16KB)
#define ASCR 16384u  // 8 waves x 2KB transpose scratch
extern "C" __global__ __launch_bounds__(512, 4)
void attn_kernel(char* __restrict__ qOb, const char* __restrict__ kvb) {
    extern __shared__ char smem[];
    const int tid = threadIdx.x;
    const int wid = tid >> 6, lane = tid & 63, l16 = lane & 15, quad = lane >> 4;
    const int win = blockIdx.x >> 3, head = blockIdx.x & 7;
    const size_t wrow0 = (size_t)win * 128;
    f32x4 zero4 = { 0.f, 0.f, 0.f, 0.f };

    // stage vT[dim][key] from v rows
    {
        int key = tid >> 2, d0 = (tid & 3) * 16;
        const char* vs = kvb + (wrow0 + key) * 2048 + 1024 + head * 128 + d0 * 2;
#pragma unroll
        for (int j = 0; j < 2; ++j) {
            bf16x8 v = *(const bf16x8*)(vs + j * 16);
#pragma unroll
            for (int e = 0; e < 8; ++e)
                *(bf16*)(smem + swz(AVT, d0 + j * 8 + e, 256, key * 2)) = v[e];
        }
    }
    __syncthreads();  // only barrier in this kernel

    // q fragments (A layout, direct from global)
    bf16x8 qf[2];
#pragma unroll
    for (int ks = 0; ks < 2; ++ks)
        qf[ks] = *(const bf16x8*)(qOb + (wrow0 + wid * 16 + l16) * 1024 + head * 128 + ks * 64 + quad * 16);

    // scores (k B-frags direct from global)
    f32x4 sa[8];
#pragma unroll
    for (int nt = 0; nt < 8; ++nt) sa[nt] = zero4;
#pragma unroll
    for (int nt = 0; nt < 8; ++nt)
#pragma unroll
        for (int ks = 0; ks < 2; ++ks) {
            bf16x8 kb = *(const bf16x8*)(kvb + (wrow0 + nt * 16 + l16) * 2048 + head * 128 + ks * 64 + quad * 16);
            sa[nt] = MFMA16(qf[ks], kb, sa[nt]);
        }
#pragma unroll
    for (int nt = 0; nt < 8; ++nt) sa[nt] *= 0.125f;
#pragma unroll
    for (int r = 0; r < 4; ++r) {
        float m = sa[0][r];
#pragma unroll
        for (int nt = 1; nt < 8; ++nt) m = fmaxf(m, sa[nt][r]);
#pragma unroll
        for (int sft = 1; sft < 16; sft <<= 1) m = fmaxf(m, __shfl_xor(m, sft, 64));
        float s = 0.f;
#pragma unroll
        for (int nt = 0; nt < 8; ++nt) {
            float e = __expf(sa[nt][r] - m);
            sa[nt][r] = e;
            s += e;
        }
#pragma unroll
        for (int sft = 1; sft < 16; sft <<= 1) s += __shfl_xor(s, sft, 64);
        float inv = 1.0f / s;
#pragma unroll
        for (int nt = 0; nt < 8; ++nt) sa[nt][r] *= inv;
    }

    // P C->A transpose through wave-private scratch
    const uint32_t sb = ASCR + (uint32_t)wid * 2048;
    bf16x8 pf[4];
#pragma unroll
    for (int hf = 0; hf < 2; ++hf) {
#pragma unroll
        for (int nt = 0; nt < 4; ++nt)
#pragma unroll
            for (int r = 0; r < 4; ++r)
                *(bf16*)(smem + swz(sb, quad * 4 + r, 128, (nt * 16 + l16) * 2)) = (bf16)sa[hf * 4 + nt][r];
        asm volatile("s_waitcnt lgkmcnt(0)" ::: "memory");
#pragma unroll
        for (int ks = 0; ks < 2; ++ks)
            pf[hf * 2 + ks] = *(bf16x8*)(smem + swz(sb, l16, 128, ks * 64 + quad * 16));
        asm volatile("s_waitcnt lgkmcnt(0)" ::: "memory");
    }

    // O = P @ V
    f32x4 ov[4];
#pragma unroll
    for (int nt = 0; nt < 4; ++nt) {
        ov[nt] = zero4;
#pragma unroll
        for (int ks = 0; ks < 4; ++ks) {
            bf16x8 vb = *(bf16x8*)(smem + swz(AVT, nt * 16 + l16, 256, ks * 64 + quad * 16));
            ov[nt] = MFMA16(pf[ks], vb, ov[nt]);
        }
    }
    // O store via transpose: two 32-col halves through 2KB wave scratch (rs=128)
#pragma unroll
    for (int hf = 0; hf < 2; ++hf) {
#pragma unroll
        for (int nt = 0; nt < 2; ++nt)
#pragma unroll
            for (int r = 0; r < 4; ++r)
                *(bf16*)(smem + swz(sb, quad * 4 + r, 128, (nt * 16 + l16) * 2)) = (bf16)ov[hf * 2 + nt][r];
        asm volatile("s_waitcnt lgkmcnt(0)" ::: "memory");
        {
            int row = lane >> 2, ch = lane & 3;
            bf16x8 v = *(bf16x8*)(smem + swz(sb, row, 128, ch * 16));
            *(bf16x8*)(qOb + (wrow0 + wid * 16 + row) * 1024 + head * 128 + hf * 64 + ch * 16) = v;
        }
        asm volatile("s_waitcnt lgkmcnt(0)" ::: "memory");
    }
}

// ---------- out-proj v2 + residual + LN1: M=32768 N=512 K=512 ----------
// 128x512 tile (grid 256), 8 waves (2x4), wave tile 64x128; BK=32, 16 iters.
// B staged COALESCED from k-tile-major Wout'; A from qOb (stride 1024).
// Epilogue: bias + residual(x) + LN1 -> bf16 x1 via transpose-store.
extern "C" __global__ __launch_bounds__(512, 2)
void outproj_kernel(char* __restrict__ srcb, const char* __restrict__ qOb,
                    const char* __restrict__ Woutp, const float* __restrict__ bout,
                    const float* __restrict__ g1, const float* __restrict__ be1) {
    extern __shared__ char smem[];
    const int tid = threadIdx.x;
    const int w = tid >> 6, lane = tid & 63, l16 = lane & 15, quad = lane >> 4;
    const int wm = w >> 2, wn = w & 3;
    const int mb = blockIdx.x;

    f32x4 acc[4][8];
#pragma unroll
    for (int i = 0; i < 4; ++i)
#pragma unroll
        for (int nt = 0; nt < 8; ++nt) acc[i][nt] = (f32x4){0.f, 0.f, 0.f, 0.f};

#define OP_STAGE(buf, t)                                                               \
    {                                                                                  \
        int ca = w >> 1, rg = w & 1; /* A: 8 wave-issues (gathered O rows) */          \
        gload16(qOb + (size_t)(mb * 128 + rg * 64 + lane) * 1024 + (t) * 64 + ca * 16, \
                smem + (uint32_t)(buf) * 8192u + ca * 2048 + rg * 1024);               \
        _Pragma("unroll")                                                              \
        for (int j = 0; j < 4; ++j) { /* B: 32 wave-issues, contiguous 1KB each */     \
            int idx = w * 4 + j, c = idx >> 3, ng = idx & 7;                           \
            gload16(Woutp + (size_t)(t) * 32768 + c * 8192 + ng * 1024 + lane * 16,    \
                    smem + 16384u + (uint32_t)(buf) * 32768u + (uint32_t)c * 8192 + (uint32_t)ng * 1024); \
        }                                                                              \
    }

    OP_STAGE(0, 0);
    __syncthreads();

#pragma unroll 1
    for (int t = 0; t < 16; ++t) {
        if (t < 15) OP_STAGE((t + 1) & 1, t + 1);
        const uint32_t A0 = (uint32_t)(t & 1) * 8192u;
        const uint32_t B0 = 16384u + (uint32_t)(t & 1) * 32768u;
        bf16x8 a[4];
#pragma unroll
        for (int i = 0; i < 4; ++i)
            a[i] = *(const bf16x8*)(smem + A0 + quad * 2048 + (wm * 64 + i * 16 + l16) * 16);
#pragma unroll
        for (int nt = 0; nt < 8; ++nt) {
            bf16x8 b = *(const bf16x8*)(smem + B0 + quad * 8192 + (wn * 128 + nt * 16 + l16) * 16);
#pragma unroll
            for (int i = 0; i < 4; ++i) acc[i][nt] = MFMA16(a[i], b, acc[i][nt]);
        }
        __syncthreads();
    }
#undef OP_STAGE

    // ---- bias + residual(x bf16) ----
#pragma unroll
    for (int nt = 0; nt < 8; ++nt) {
        int col = wn * 128 + nt * 16 + l16;
        float bb = bout[col];
#pragma unroll
        for (int i = 0; i < 4; ++i)
#pragma unroll
            for (int r = 0; r < 4; ++r) {
                int row = mb * 128 + wm * 64 + i * 16 + quad * 4 + r;
                float xv = (float)*(const bf16*)(srcb + (size_t)row * 2048 + col * 2);
                acc[i][nt][r] += bb + xv;
            }
    }
    // per-(row, wave) partials over this wave's 128 cols
    float ps[4][4], ps2[4][4];
#pragma unroll
    for (int i = 0; i < 4; ++i)
#pragma unroll
        for (int r = 0; r < 4; ++r) {
            float s = 0.f, s2 = 0.f;
#pragma unroll
            for (int nt = 0; nt < 8; ++nt) {
                float v = acc[i][nt][r];
                s += v;
                s2 += v * v;
            }
#pragma unroll
            for (int sft = 1; sft < 16; sft <<= 1) {
                s += __shfl_xor(s, sft, 64);
                s2 += __shfl_xor(s2, sft, 64);
            }
            ps[i][r] = s;
            ps2[i][r] = s2;
        }
    // cross-wave reduce via LDS scratch (dead A-buf): [128 rows][4 wn][2 f32]
    if (l16 == 0) {
#pragma unroll
        for (int i = 0; i < 4; ++i)
#pragma unroll
            for (int r = 0; r < 4; ++r) {
                int row_l = wm * 64 + i * 16 + quad * 4 + r;
                *(float*)(smem + row_l * 32 + wn * 8) = ps[i][r];
                *(float*)(smem + row_l * 32 + wn * 8 + 4) = ps2[i][r];
            }
    }
    __syncthreads();
    // per-i: LN1 + 16x128 transpose-store of bf16 x1 into srcb[1024:2048)
    const uint32_t sb = 16384u + (uint32_t)w * 4096u;  // dead B-buf0
#pragma unroll
    for (int i = 0; i < 4; ++i) {
#pragma unroll
        for (int r = 0; r < 4; ++r) {
            int row_l = wm * 64 + i * 16 + quad * 4 + r;
            float S = 0.f, S2 = 0.f;
#pragma unroll
            for (int w4 = 0; w4 < 4; ++w4) {
                S += *(const float*)(smem + row_l * 32 + w4 * 8);
                S2 += *(const float*)(smem + row_l * 32 + w4 * 8 + 4);
            }
            float mu = S * (1.0f / 512.0f);
            float var = S2 * (1.0f / 512.0f) - mu * mu;
            float rstd = rsqrtf(var + 1e-5f);
#pragma unroll
            for (int nt = 0; nt < 8; ++nt) {
                int col = wn * 128 + nt * 16 + l16;
                float v = (acc[i][nt][r] - mu) * rstd * g1[col] + be1[col];
                *(bf16*)(smem + swz(sb, quad * 4 + r, 256, (nt * 16 + l16) * 2)) = (bf16)v;
            }
        }
        asm volatile("s_waitcnt lgkmcnt(0)" ::: "memory");
#pragma unroll
        for (int j = 0; j < 4; ++j) {
            int uu = j * 64 + lane;
            int row = uu >> 4, ch = uu & 15;
            bf16x8 v = *(bf16x8*)(smem + swz(sb, row, 256, ch * 16));
            *(bf16x8*)(srcb + (size_t)(mb * 128 + wm * 64 + i * 16 + row) * 2048 + 1024 +
                       wn * 256 + ch * 16) = v;
        }
        asm volatile("s_waitcnt lgkmcnt(0)" ::: "memory");
    }
}

// ---------- FF1 v3: M=32768 N=2048 K=512; 128x512 tile, grid (256,4) ----------
// 8 waves (2x4), wave tile 64x128; BK=32, 16 iters; A+B dbuf via gload_lds.
// B staged COALESCED from k-tile-major W1' (LDS image == global image).
// LDS: A 2x8KB at 0; B 2x32KB at 16384. Total 80KB, 1 block/CU.
extern "C" __global__ __launch_bounds__(512, 2)
void ff1_kernel(char* __restrict__ srcb, const char* __restrict__ W1p,
                const float* __restrict__ b1, char* __restrict__ doutb,
                char* __restrict__ wsOb) {
    extern __shared__ char smem[];
    const int tid = threadIdx.x;
    const int w = tid >> 6, lane = tid & 63, l16 = lane & 15, quad = lane >> 4;
    const int wm = w >> 2, wn = w & 3;
    const int mb = blockIdx.x, cb = blockIdx.y;

    f32x4 acc[4][8];
#pragma unroll
    for (int i = 0; i < 4; ++i)
#pragma unroll
        for (int nt = 0; nt < 8; ++nt) acc[i][nt] = (f32x4){0.f, 0.f, 0.f, 0.f};

#define FF1_STAGE(buf, t)                                                              \
    {                                                                                  \
        int ca = w >> 1, rg = w & 1; /* A: 8 wave-issues (gathered rows) */            \
        gload16(srcb + (size_t)(mb * 128 + rg * 64 + lane) * 2048 + 1024 + (t) * 64 + ca * 16, \
                smem + (uint32_t)(buf) * 8192u + ca * 2048 + rg * 1024);               \
        _Pragma("unroll")                                                              \
        for (int j = 0; j < 4; ++j) { /* B: 32 wave-issues, contiguous 1KB each */     \
            int idx = w * 4 + j, c = idx >> 3, ng = idx & 7;                           \
            gload16(W1p + (size_t)(cb * 16 + (t)) * 32768 + c * 8192 + ng * 1024 + lane * 16, \
                    smem + 16384u + (uint32_t)(buf) * 32768u + (uint32_t)c * 8192 + (uint32_t)ng * 1024); \
        }                                                                              \
    }

    FF1_STAGE(0, 0);
    __syncthreads();

#pragma unroll 1
    for (int t = 0; t < 16; ++t) {
        if (t < 15) FF1_STAGE((t + 1) & 1, t + 1);
        const uint32_t A0 = (uint32_t)(t & 1) * 8192u;
        const uint32_t B0 = 16384u + (uint32_t)(t & 1) * 32768u;
        bf16x8 a[4];
#pragma unroll
        for (int i = 0; i < 4; ++i)
            a[i] = *(const bf16x8*)(smem + A0 + quad * 2048 + (wm * 64 + i * 16 + l16) * 16);
#pragma unroll
        for (int nt = 0; nt < 8; ++nt) {
            bf16x8 b = *(const bf16x8*)(smem + B0 + quad * 8192 + (wn * 128 + nt * 16 + l16) * 16);
#pragma unroll
            for (int i = 0; i < 4; ++i) acc[i][nt] = MFMA16(a[i], b, acc[i][nt]);
        }
        __syncthreads();  // drains this iter's prefetch; next buffer ready
    }
#undef FF1_STAGE

    // epilogue: bias+relu; per-i 16x128-col transpose through 4KB wave scratch
    const uint32_t sb = 16384u + (uint32_t)w * 4096u;  // dead B-buf0 region
#pragma unroll
    for (int i = 0; i < 4; ++i) {
#pragma unroll
        for (int nt = 0; nt < 8; ++nt) {
            float bb = b1[cb * 512 + wn * 128 + nt * 16 + l16];
#pragma unroll
            for (int r = 0; r < 4; ++r)
                *(bf16*)(smem + swz(sb, quad * 4 + r, 256, (nt * 16 + l16) * 2)) =
                    (bf16)fmaxf(acc[i][nt][r] + bb, 0.0f);
        }
        asm volatile("s_waitcnt lgkmcnt(0)" ::: "memory");
#pragma unroll
        for (int j = 0; j < 4; ++j) {
            int uu = j * 64 + lane;  // 0..255: 16 rows x 16 chunks
            int row = uu >> 4, ch = uu & 15;
            bf16x8 v = *(bf16x8*)(smem + swz(sb, row, 256, ch * 16));
            size_t row_g = (size_t)(mb * 128 + wm * 64 + i * 16 + row);
            int nb2 = wn * 256 + ch * 16;  // byte within this cb's 1024B col-slice
            if (cb < 2)       *(bf16x8*)(doutb + row_g * 2048 + cb * 1024 + nb2) = v;
            else if (cb == 2) *(bf16x8*)(srcb + row_g * 2048 + nb2) = v;
            else              *(bf16x8*)(wsOb + row_g * 1024 + nb2) = v;
        }
        asm volatile("s_waitcnt lgkmcnt(0)" ::: "memory");
    }
}

// ---------- FF2 v5 + residual + LN2: M=32768 N=512 K=2048 -> f32 out ----------
// 128x512 tile (grid 256), 8 waves (2x4), wave tile 64x128; BK=32, 64 iters.
// B staged COALESCED from k-tile-major W2'; A (h, 3-region) staged gathered.
// LDS: A 2x8KB at 0; B 2x32KB at 16384. Total 80KB, 1 block/CU.
extern "C" __global__ __launch_bounds__(512, 2)
void ff2_kernel(char* __restrict__ doutb, const char* __restrict__ srcb,
                const char* __restrict__ wsOb, const char* __restrict__ W2p,
                const float* __restrict__ b2, const float* __restrict__ g2,
                const float* __restrict__ be2) {
    extern __shared__ char smem[];
    const int tid = threadIdx.x;
    const int w = tid >> 6, lane = tid & 63, l16 = lane & 15, quad = lane >> 4;
    const int wm = w >> 2, wn = w & 3;
    const int mb = blockIdx.x;

    f32x4 acc[4][8];
#pragma unroll
    for (int i = 0; i < 4; ++i)
#pragma unroll
        for (int nt = 0; nt < 8; ++nt) acc[i][nt] = (f32x4){0.f, 0.f, 0.f, 0.f};

#define FF2_STAGE(buf, t)                                                              \
    {                                                                                  \
        const char* hb; int rstride, koffb;                                            \
        if ((t) < 32)      { hb = doutb; rstride = 2048; koffb = (t) * 64; }           \
        else if ((t) < 48) { hb = srcb;  rstride = 2048; koffb = ((t) - 32) * 64; }    \
        else               { hb = wsOb;  rstride = 1024; koffb = ((t) - 48) * 64; }    \
        int ca = w >> 1, rg = w & 1; /* A: 8 wave-issues (gathered h rows) */          \
        gload16(hb + (size_t)(mb * 128 + rg * 64 + lane) * rstride + koffb + ca * 16,  \
                smem + (uint32_t)(buf) * 8192u + ca * 2048 + rg * 1024);               \
        _Pragma("unroll")                                                              \
        for (int j = 0; j < 4; ++j) { /* B: 32 wave-issues, contiguous 1KB each */     \
            int idx = w * 4 + j, c = idx >> 3, ng = idx & 7;                           \
            gload16(W2p + (size_t)(t) * 32768 + c * 8192 + ng * 1024 + lane * 16,      \
                    smem + 16384u + (uint32_t)(buf) * 32768u + (uint32_t)c * 8192 + (uint32_t)ng * 1024); \
        }                                                                              \
    }

    FF2_STAGE(0, 0);
    __syncthreads();

#pragma unroll 1
    for (int t = 0; t < 64; ++t) {
        if (t < 63) FF2_STAGE((t + 1) & 1, t + 1);
        const uint32_t A0 = (uint32_t)(t & 1) * 8192u;
        const uint32_t B0 = 16384u + (uint32_t)(t & 1) * 32768u;
        bf16x8 a[4];
#pragma unroll
        for (int i = 0; i < 4; ++i)
            a[i] = *(const bf16x8*)(smem + A0 + quad * 2048 + (wm * 64 + i * 16 + l16) * 16);
#pragma unroll
        for (int nt = 0; nt < 8; ++nt) {
            bf16x8 b = *(const bf16x8*)(smem + B0 + quad * 8192 + (wn * 128 + nt * 16 + l16) * 16);
#pragma unroll
            for (int i = 0; i < 4; ++i) acc[i][nt] = MFMA16(a[i], b, acc[i][nt]);
        }
        __syncthreads();  // drains this iter's prefetch; next buffer ready
    }
#undef FF2_STAGE

    // ---- epilogue: bias + residual(x1) + LN2 over full 512-col rows ----
#pragma unroll
    for (int nt = 0; nt < 8; ++nt) {
        int col = wn * 128 + nt * 16 + l16;
        float bb = b2[col];
#pragma unroll
        for (int i = 0; i < 4; ++i)
#pragma unroll
            for (int r = 0; r < 4; ++r) {
                int row = mb * 128 + wm * 64 + i * 16 + quad * 4 + r;
                float x1v = (float)*(const bf16*)(srcb + (size_t)row * 2048 + 1024 + col * 2);
                acc[i][nt][r] += bb + x1v;
            }
    }
    // per-(row, wave) partials over this wave's 128 cols
    float ps[4][4], ps2[4][4];
#pragma unroll
    for (int i = 0; i < 4; ++i)
#pragma unroll
        for (int r = 0; r < 4; ++r) {
            float s = 0.f, s2 = 0.f;
#pragma unroll
            for (int nt = 0; nt < 8; ++nt) {
                float v = acc[i][nt][r];
                s += v;
                s2 += v * v;
            }
#pragma unroll
            for (int sft = 1; sft < 16; sft <<= 1) {
                s += __shfl_xor(s, sft, 64);
                s2 += __shfl_xor(s2, sft, 64);
            }
            ps[i][r] = s;
            ps2[i][r] = s2;
        }
    // cross-wave reduce via LDS scratch (A-buf region dead): [128 rows][4 wn][2 f32]
    if (l16 == 0) {
#pragma unroll
        for (int i = 0; i < 4; ++i)
#pragma unroll
            for (int r = 0; r < 4; ++r) {
                int row_l = wm * 64 + i * 16 + quad * 4 + r;
                *(float*)(smem + row_l * 32 + wn * 8) = ps[i][r];
                *(float*)(smem + row_l * 32 + wn * 8 + 4) = ps2[i][r];
            }
    }
    __syncthreads();
#pragma unroll
    for (int i = 0; i < 4; ++i)
#pragma unroll
        for (int r = 0; r < 4; ++r) {
            int row_l = wm * 64 + i * 16 + quad * 4 + r;
            float S = 0.f, S2 = 0.f;
#pragma unroll
            for (int w4 = 0; w4 < 4; ++w4) {
                S += *(const float*)(smem + row_l * 32 + w4 * 8);
                S2 += *(const float*)(smem + row_l * 32 + w4 * 8 + 4);
            }
            float mu = S * (1.0f / 512.0f);
            float var = S2 * (1.0f / 512.0f) - mu * mu;
            float rstd = rsqrtf(var + 1e-5f);
            size_t row = (size_t)(mb * 128 + row_l);
#pragma unroll
            for (int nt = 0; nt < 8; ++nt) {
                int col = wn * 128 + nt * 16 + l16;
                *(float*)(doutb + row * 2048 + col * 4) =
                    (acc[i][nt][r] - mu) * rstd * g2[col] + be2[col];
            }
        }
}

extern "C" void kernel_launch(void* const* d_in, const int* in_sizes, int n_in,
                              void* d_out, int out_size, void* d_ws, size_t ws_size,
                              hipStream_t stream) {
    (void)in_sizes; (void)n_in; (void)out_size; (void)ws_size;
    float* src = (float*)d_in[0];
    const float* ipw = (const float*)d_in[1];
    const float* ipb = (const float*)d_in[2];
    const float* ow  = (const float*)d_in[3];
    const float* ob  = (const float*)d_in[4];
    const float* g1  = (const float*)d_in[5];
    const float* be1 = (const float*)d_in[6];
    const float* w1  = (const float*)d_in[7];
    const float* b1  = (const float*)d_in[8];
    const float* w2  = (const float*)d_in[9];
    const float* b2  = (const float*)d_in[10];
    const float* g2  = (const float*)d_in[11];
    const float* be2 = (const float*)d_in[12];
    bf16* ws = (bf16*)d_ws;
    char* srcb = (char*)src;
    char* doutb = (char*)d_out;
    char* qOb = (char*)d_ws + 6291456;  // 33.5 MB q/O/h-tail region

    wcvt_kernel<<<1536, 256, 0, stream>>>(ipw, ow, w1, w2, ws);
    xcvt_kernel<<<8192, 256, 0, stream>>>(src);

    hipFuncSetAttribute((const void*)qkv_kernel, hipFuncAttributeMaxDynamicSharedMemorySize, 81920);
    hipFuncSetAttribute((const void*)attn_kernel, hipFuncAttributeMaxDynamicSharedMemorySize, 32768);
    hipFuncSetAttribute((const void*)outproj_kernel, hipFuncAttributeMaxDynamicSharedMemorySize, 81920);
    hipFuncSetAttribute((const void*)ff1_kernel, hipFuncAttributeMaxDynamicSharedMemorySize, 81920);
    hipFuncSetAttribute((const void*)ff2_kernel, hipFuncAttributeMaxDynamicSharedMemorySize, 81920);

    qkv_kernel<<<dim3(256, 3), 512, 81920, stream>>>(srcb, (const char*)ws, ipb, qOb, doutb);
    attn_kernel<<<2048, 512, 32768, stream>>>(qOb, doutb);
    outproj_kernel<<<256, 512, 81920, stream>>>(srcb, qOb, (const char*)(ws + 786432), ob, g1, be1);
    ff1_kernel<<<dim3(256, 4), 512, 81920, stream>>>(srcb, (const char*)(ws + 1048576), b1, doutb, qOb);
    ff2_kernel<<<256, 512, 81920, stream>>>(doutb, srcb, qOb, (const char*)(ws + 2097152), b2, g2, be2);
}

// Round 5
// 497.252 us; speedup vs baseline: 1.8191x; 1.0546x over previous
//
#include <hip/hip_runtime.h>
#include <hip/hip_bf16.h>
#include <math.h>

typedef __bf16 bf16;
typedef bf16 bf16x8 __attribute__((ext_vector_type(8)));
typedef bf16 bf16x4 __attribute__((ext_vector_type(4)));
typedef float f32x4 __attribute__((ext_vector_type(4)));

#define MFMA16(a, b, c) __builtin_amdgcn_mfma_f32_16x16x32_bf16(a, b, c, 0, 0, 0)

// XOR-swizzle on 16B chunks within a row: breaks power-of-2 row-stride bank aliasing.
__device__ __forceinline__ uint32_t swz(uint32_t base, uint32_t row, uint32_t rs, uint32_t cb) {
    return base + row * rs + (((cb >> 4) ^ (row & 7u)) << 4) + (cb & 15u);
}

// async global->LDS, 16B per lane. LDS dest = wave-uniform base + lane*16 (linear).
__device__ __forceinline__ void gload16(const void* g, void* l) {
    __builtin_amdgcn_global_load_lds((const __attribute__((address_space(1))) void*)g,
                                     (__attribute__((address_space(3))) void*)l, 16, 0, 0);
}

// Pipeline LDS layout (3-deep, counted-vmcnt):
//  A bufs: ib*8192, ib in {0,1,2}  -> [0, 24576)
//  B bufs: 24576 + ib*32768        -> [24576, 122880)
// Each STAGE = 5 gload16 per wave (1 A + 4 B). Main loop keeps the next TWO
// batches in flight: s_waitcnt vmcnt(5) retires only the older batch (T4:
// never drain to 0 in the loop), raw s_barrier for the LDS handshake.

// Scratch map (row r = one of 32768 tokens):
//  src  slice r*2048B: [0,1024)=x_bf16 (xcvt; dead after outproj) -> h[1024:1536]
//                      [1024,2048)=x1 bf16 (outproj; read ff1, ff2-residual)
//  dout slice r*2048B: [0,1024)=k, [1024,2048)=v (qkv; dead after attn)
//                      -> h[0:1024] (ff1) -> final f32 out row (ff2, after h consumed)
//  ws: [0,6.3MB)=bf16 weights; [6.3,39.8MB) r*1024B: q (qkv) -> O (attn, same
//      block/cols) -> h[1536:2048] (ff1)
// Weight region layout (bf16 elems), ALL k-tile-major "LDS image" [tile][c][nn]:
//  unit u = 8 elems; within a region: tile=u>>11, c=(u>>9)&3, nn=u&511;
//  tile is 32KB = one K-step's B-panel; k = (tile%T_K)*32 + c*8, T_K = K/32.
//  Wqkv' [0,786432):        48 tiles; n=(tile>>4)*512+nn, k=(tile&15)*32+c*8
//  Wout' [786432,1048576):  16 tiles; n=nn, k=tile*32+c*8
//  W1'  [1048576,2097152): 128 tiles; n=(tile>>4)*512+nn, k=(tile&15)*32+c*8
//  W2'  [2097152,3145728):  64 tiles; n=nn, k=t*32+c*8

// ---------- weights f32 -> bf16, k-tile-major repack ----------
__global__ void wcvt_kernel(const float* __restrict__ wqkv, const float* __restrict__ wout,
                            const float* __restrict__ w1f, const float* __restrict__ w2f,
                            bf16* __restrict__ o) {
    int i = blockIdx.x * blockDim.x + threadIdx.x;  // one 8-elem unit
    const float* s;
    int soff, doff;
    if (i < 98304) {  // Wqkv: [1536][512] -> 48 tiles
        int u = i;
        int tile = u >> 11, c = (u >> 9) & 3, nn = u & 511;
        int n = (tile >> 4) * 512 + nn;
        int k = (tile & 15) * 32 + c * 8;
        s = wqkv; soff = n * 512 + k; doff = u * 8;
    } else if (i < 131072) {  // Wout: [512][512] -> 16 tiles
        int u = i - 98304;
        int tile = u >> 11, c = (u >> 9) & 3, nn = u & 511;
        int k = tile * 32 + c * 8;
        s = wout; soff = nn * 512 + k; doff = 786432 + u * 8;
    } else if (i < 262144) {  // W1: [2048][512] -> 128 tiles
        int u = i - 131072;
        int tile = u >> 11, c = (u >> 9) & 3, nn = u & 511;
        int n = (tile >> 4) * 512 + nn;
        int k = (tile & 15) * 32 + c * 8;
        s = w1f; soff = n * 512 + k; doff = 1048576 + u * 8;
    } else {  // W2: [512][2048] -> 64 tiles
        int u = i - 262144;
        int t = u >> 11, c = (u >> 9) & 3, nn = u & 511;
        int k = t * 32 + c * 8;
        s = w2f; soff = nn * 2048 + k; doff = 2097152 + u * 8;
    }
    float4 v0 = *(const float4*)(s + soff);
    float4 v1 = *(const float4*)(s + soff + 4);
    bf16x8 h = { (bf16)v0.x, (bf16)v0.y, (bf16)v0.z, (bf16)v0.w,
                 (bf16)v1.x, (bf16)v1.y, (bf16)v1.z, (bf16)v1.w };
    *(bf16x8*)(o + doff) = h;
}

// ---------- src f32 -> bf16 in place (row-aligned slot; wave per row) ----------
__global__ void xcvt_kernel(float* __restrict__ src) {
    int row = blockIdx.x * 4 + (threadIdx.x >> 6);
    int l = threadIdx.x & 63;
    float* rp = src + (size_t)row * 512 + l * 8;
    float4 v0 = *(const float4*)rp;
    float4 v1 = *(const float4*)(rp + 4);
    asm volatile("s_waitcnt vmcnt(0)" ::: "memory");  // all wave reads before any write
    bf16x8 h = { (bf16)v0.x, (bf16)v0.y, (bf16)v0.z, (bf16)v0.w,
                 (bf16)v1.x, (bf16)v1.y, (bf16)v1.z, (bf16)v1.w };
    *(bf16x8*)((bf16*)(src + (size_t)row * 512) + l * 8) = h;
}

// ---------- qkv GEMM v3: M=32768 N=1536 K=512; 128x512 tile, grid (256,3) ----------
// 3-deep pipelined staging, counted vmcnt(5); 8 waves, wave tile 64x128.
extern "C" __global__ __launch_bounds__(512, 2)
void qkv_kernel(const char* __restrict__ xb, const char* __restrict__ Wqkvp,
                const float* __restrict__ bqkv, char* __restrict__ qOb,
                char* __restrict__ kvb) {
    extern __shared__ char smem[];
    const int tid = threadIdx.x;
    const int w = tid >> 6, lane = tid & 63, l16 = lane & 15, quad = lane >> 4;
    const int wm = w >> 2, wn = w & 3;
    const int mb = blockIdx.x, cb = blockIdx.y;

    f32x4 acc[4][8];
#pragma unroll
    for (int i = 0; i < 4; ++i)
#pragma unroll
        for (int nt = 0; nt < 8; ++nt) acc[i][nt] = (f32x4){0.f, 0.f, 0.f, 0.f};

#define QKV_STAGE(ib, t)                                                               \
    {                                                                                  \
        int ca = w >> 1, rg = w & 1; /* A: 8 wave-issues (gathered x rows) */          \
        gload16(xb + (size_t)(mb * 128 + rg * 64 + lane) * 2048 + (t) * 64 + ca * 16,  \
                smem + (uint32_t)(ib) * 8192u + ca * 2048 + rg * 1024);                \
        _Pragma("unroll")                                                              \
        for (int j = 0; j < 4; ++j) { /* B: 32 wave-issues, contiguous 1KB each */     \
            int idx = w * 4 + j, c = idx >> 3, ng = idx & 7;                           \
            gload16(Wqkvp + (size_t)(cb * 16 + (t)) * 32768 + c * 8192 + ng * 1024 + lane * 16, \
                    smem + 24576u + (uint32_t)(ib) * 32768u + (uint32_t)c * 8192 + (uint32_t)ng * 1024); \
        }                                                                              \
    }

    QKV_STAGE(0, 0);
    QKV_STAGE(1, 1);
    asm volatile("s_waitcnt vmcnt(5)" ::: "memory");
    __builtin_amdgcn_s_barrier();

    int ib = 0;
#pragma unroll 1
    for (int t = 0; t < 16; ++t) {
        int in2 = ib + 2; if (in2 >= 3) in2 -= 3;
        if (t + 2 < 16) QKV_STAGE(in2, t + 2);
        const uint32_t A0 = (uint32_t)ib * 8192u;
        const uint32_t B0 = 24576u + (uint32_t)ib * 32768u;
        bf16x8 a[4];
#pragma unroll
        for (int i = 0; i < 4; ++i)
            a[i] = *(const bf16x8*)(smem + A0 + quad * 2048 + (wm * 64 + i * 16 + l16) * 16);
#pragma unroll
        for (int nt = 0; nt < 8; ++nt) {
            bf16x8 b = *(const bf16x8*)(smem + B0 + quad * 8192 + (wn * 128 + nt * 16 + l16) * 16);
#pragma unroll
            for (int i = 0; i < 4; ++i) acc[i][nt] = MFMA16(a[i], b, acc[i][nt]);
        }
        if (t + 2 < 16) asm volatile("s_waitcnt vmcnt(5)" ::: "memory");
        else            asm volatile("s_waitcnt vmcnt(0)" ::: "memory");
        __builtin_amdgcn_s_barrier();
        ib = (ib == 2) ? 0 : ib + 1;
    }
#undef QKV_STAGE

    // epilogue: bias; per-i 16x128 transpose through 4KB wave scratch (dead B region)
    const uint32_t sb = 24576u + (uint32_t)w * 4096u;
#pragma unroll
    for (int i = 0; i < 4; ++i) {
#pragma unroll
        for (int nt = 0; nt < 8; ++nt) {
            float bb = bqkv[cb * 512 + wn * 128 + nt * 16 + l16];
#pragma unroll
            for (int r = 0; r < 4; ++r)
                *(bf16*)(smem + swz(sb, quad * 4 + r, 256, (nt * 16 + l16) * 2)) =
                    (bf16)(acc[i][nt][r] + bb);
        }
        asm volatile("s_waitcnt lgkmcnt(0)" ::: "memory");
#pragma unroll
        for (int j = 0; j < 4; ++j) {
            int uu = j * 64 + lane;  // 16 rows x 16 chunks
            int row = uu >> 4, ch = uu & 15;
            bf16x8 v = *(bf16x8*)(smem + swz(sb, row, 256, ch * 16));
            size_t row_g = (size_t)(mb * 128 + wm * 64 + i * 16 + row);
            int nb2 = wn * 256 + ch * 16;  // byte within this cb's 1024B col-slice
            if (cb == 0)      *(bf16x8*)(qOb + row_g * 1024 + nb2) = v;
            else if (cb == 1) *(bf16x8*)(kvb + row_g * 2048 + nb2) = v;
            else              *(bf16x8*)(kvb + row_g * 2048 + 1024 + nb2) = v;
        }
        asm volatile("s_waitcnt lgkmcnt(0)" ::: "memory");
    }
}

// ---------- attention: one block per (window, head) ----------
#define AVT 0u       // vT 64x128 bf16 rs=256B (16KB)
#define ASCR 16384u  // 8 waves x 2KB transpose scratch
extern "C" __global__ __launch_bounds__(512, 4)
void attn_kernel(char* __restrict__ qOb, const char* __restrict__ kvb) {
    extern __shared__ char smem[];
    const int tid = threadIdx.x;
    const int wid = tid >> 6, lane = tid & 63, l16 = lane & 15, quad = lane >> 4;
    const int win = blockIdx.x >> 3, head = blockIdx.x & 7;
    const size_t wrow0 = (size_t)win * 128;
    f32x4 zero4 = { 0.f, 0.f, 0.f, 0.f };

    // stage vT[dim][key] from v rows
    {
        int key = tid >> 2, d0 = (tid & 3) * 16;
        const char* vs = kvb + (wrow0 + key) * 2048 + 1024 + head * 128 + d0 * 2;
#pragma unroll
        for (int j = 0; j < 2; ++j) {
            bf16x8 v = *(const bf16x8*)(vs + j * 16);
#pragma unroll
            for (int e = 0; e < 8; ++e)
                *(bf16*)(smem + swz(AVT, d0 + j * 8 + e, 256, key * 2)) = v[e];
        }
    }
    __syncthreads();  // only barrier in this kernel

    // q fragments (A layout, direct from global)
    bf16x8 qf[2];
#pragma unroll
    for (int ks = 0; ks < 2; ++ks)
        qf[ks] = *(const bf16x8*)(qOb + (wrow0 + wid * 16 + l16) * 1024 + head * 128 + ks * 64 + quad * 16);

    // scores (k B-frags direct from global)
    f32x4 sa[8];
#pragma unroll
    for (int nt = 0; nt < 8; ++nt) sa[nt] = zero4;
#pragma unroll
    for (int nt = 0; nt < 8; ++nt)
#pragma unroll
        for (int ks = 0; ks < 2; ++ks) {
            bf16x8 kb = *(const bf16x8*)(kvb + (wrow0 + nt * 16 + l16) * 2048 + head * 128 + ks * 64 + quad * 16);
            sa[nt] = MFMA16(qf[ks], kb, sa[nt]);
        }
#pragma unroll
    for (int nt = 0; nt < 8; ++nt) sa[nt] *= 0.125f;
#pragma unroll
    for (int r = 0; r < 4; ++r) {
        float m = sa[0][r];
#pragma unroll
        for (int nt = 1; nt < 8; ++nt) m = fmaxf(m, sa[nt][r]);
#pragma unroll
        for (int sft = 1; sft < 16; sft <<= 1) m = fmaxf(m, __shfl_xor(m, sft, 64));
        float s = 0.f;
#pragma unroll
        for (int nt = 0; nt < 8; ++nt) {
            float e = __expf(sa[nt][r] - m);
            sa[nt][r] = e;
            s += e;
        }
#pragma unroll
        for (int sft = 1; sft < 16; sft <<= 1) s += __shfl_xor(s, sft, 64);
        float inv = 1.0f / s;
#pragma unroll
        for (int nt = 0; nt < 8; ++nt) sa[nt][r] *= inv;
    }

    // P C->A transpose through wave-private scratch
    const uint32_t sb = ASCR + (uint32_t)wid * 2048;
    bf16x8 pf[4];
#pragma unroll
    for (int hf = 0; hf < 2; ++hf) {
#pragma unroll
        for (int nt = 0; nt < 4; ++nt)
#pragma unroll
            for (int r = 0; r < 4; ++r)
                *(bf16*)(smem + swz(sb, quad * 4 + r, 128, (nt * 16 + l16) * 2)) = (bf16)sa[hf * 4 + nt][r];
        asm volatile("s_waitcnt lgkmcnt(0)" ::: "memory");
#pragma unroll
        for (int ks = 0; ks < 2; ++ks)
            pf[hf * 2 + ks] = *(bf16x8*)(smem + swz(sb, l16, 128, ks * 64 + quad * 16));
        asm volatile("s_waitcnt lgkmcnt(0)" ::: "memory");
    }

    // O = P @ V
    f32x4 ov[4];
#pragma unroll
    for (int nt = 0; nt < 4; ++nt) {
        ov[nt] = zero4;
#pragma unroll
        for (int ks = 0; ks < 4; ++ks) {
            bf16x8 vb = *(bf16x8*)(smem + swz(AVT, nt * 16 + l16, 256, ks * 64 + quad * 16));
            ov[nt] = MFMA16(pf[ks], vb, ov[nt]);
        }
    }
    // O store via transpose: two 32-col halves through 2KB wave scratch (rs=128)
#pragma unroll
    for (int hf = 0; hf < 2; ++hf) {
#pragma unroll
        for (int nt = 0; nt < 2; ++nt)
#pragma unroll
            for (int r = 0; r < 4; ++r)
                *(bf16*)(smem + swz(sb, quad * 4 + r, 128, (nt * 16 + l16) * 2)) = (bf16)ov[hf * 2 + nt][r];
        asm volatile("s_waitcnt lgkmcnt(0)" ::: "memory");
        {
            int row = lane >> 2, ch = lane & 3;
            bf16x8 v = *(bf16x8*)(smem + swz(sb, row, 128, ch * 16));
            *(bf16x8*)(qOb + (wrow0 + wid * 16 + row) * 1024 + head * 128 + hf * 64 + ch * 16) = v;
        }
        asm volatile("s_waitcnt lgkmcnt(0)" ::: "memory");
    }
}

// ---------- out-proj v3 + residual + LN1: M=32768 N=512 K=512 ----------
// 3-deep pipelined; epilogue: bias + residual(x) + LN1 -> bf16 x1 transpose-store.
extern "C" __global__ __launch_bounds__(512, 2)
void outproj_kernel(char* __restrict__ srcb, const char* __restrict__ qOb,
                    const char* __restrict__ Woutp, const float* __restrict__ bout,
                    const float* __restrict__ g1, const float* __restrict__ be1) {
    extern __shared__ char smem[];
    const int tid = threadIdx.x;
    const int w = tid >> 6, lane = tid & 63, l16 = lane & 15, quad = lane >> 4;
    const int wm = w >> 2, wn = w & 3;
    const int mb = blockIdx.x;

    f32x4 acc[4][8];
#pragma unroll
    for (int i = 0; i < 4; ++i)
#pragma unroll
        for (int nt = 0; nt < 8; ++nt) acc[i][nt] = (f32x4){0.f, 0.f, 0.f, 0.f};

#define OP_STAGE(ib, t)                                                                \
    {                                                                                  \
        int ca = w >> 1, rg = w & 1; /* A: 8 wave-issues (gathered O rows) */          \
        gload16(qOb + (size_t)(mb * 128 + rg * 64 + lane) * 1024 + (t) * 64 + ca * 16, \
                smem + (uint32_t)(ib) * 8192u + ca * 2048 + rg * 1024);                \
        _Pragma("unroll")                                                              \
        for (int j = 0; j < 4; ++j) { /* B: 32 wave-issues, contiguous 1KB each */     \
            int idx = w * 4 + j, c = idx >> 3, ng = idx & 7;                           \
            gload16(Woutp + (size_t)(t) * 32768 + c * 8192 + ng * 1024 + lane * 16,    \
                    smem + 24576u + (uint32_t)(ib) * 32768u + (uint32_t)c * 8192 + (uint32_t)ng * 1024); \
        }                                                                              \
    }

    OP_STAGE(0, 0);
    OP_STAGE(1, 1);
    asm volatile("s_waitcnt vmcnt(5)" ::: "memory");
    __builtin_amdgcn_s_barrier();

    int ib = 0;
#pragma unroll 1
    for (int t = 0; t < 16; ++t) {
        int in2 = ib + 2; if (in2 >= 3) in2 -= 3;
        if (t + 2 < 16) OP_STAGE(in2, t + 2);
        const uint32_t A0 = (uint32_t)ib * 8192u;
        const uint32_t B0 = 24576u + (uint32_t)ib * 32768u;
        bf16x8 a[4];
#pragma unroll
        for (int i = 0; i < 4; ++i)
            a[i] = *(const bf16x8*)(smem + A0 + quad * 2048 + (wm * 64 + i * 16 + l16) * 16);
#pragma unroll
        for (int nt = 0; nt < 8; ++nt) {
            bf16x8 b = *(const bf16x8*)(smem + B0 + quad * 8192 + (wn * 128 + nt * 16 + l16) * 16);
#pragma unroll
            for (int i = 0; i < 4; ++i) acc[i][nt] = MFMA16(a[i], b, acc[i][nt]);
        }
        if (t + 2 < 16) asm volatile("s_waitcnt vmcnt(5)" ::: "memory");
        else            asm volatile("s_waitcnt vmcnt(0)" ::: "memory");
        __builtin_amdgcn_s_barrier();
        ib = (ib == 2) ? 0 : ib + 1;
    }
#undef OP_STAGE

    // ---- bias + residual(x bf16) ----
#pragma unroll
    for (int nt = 0; nt < 8; ++nt) {
        int col = wn * 128 + nt * 16 + l16;
        float bb = bout[col];
#pragma unroll
        for (int i = 0; i < 4; ++i)
#pragma unroll
            for (int r = 0; r < 4; ++r) {
                int row = mb * 128 + wm * 64 + i * 16 + quad * 4 + r;
                float xv = (float)*(const bf16*)(srcb + (size_t)row * 2048 + col * 2);
                acc[i][nt][r] += bb + xv;
            }
    }
    // per-(row, wave) partials over this wave's 128 cols
    float ps[4][4], ps2[4][4];
#pragma unroll
    for (int i = 0; i < 4; ++i)
#pragma unroll
        for (int r = 0; r < 4; ++r) {
            float s = 0.f, s2 = 0.f;
#pragma unroll
            for (int nt = 0; nt < 8; ++nt) {
                float v = acc[i][nt][r];
                s += v;
                s2 += v * v;
            }
#pragma unroll
            for (int sft = 1; sft < 16; sft <<= 1) {
                s += __shfl_xor(s, sft, 64);
                s2 += __shfl_xor(s2, sft, 64);
            }
            ps[i][r] = s;
            ps2[i][r] = s2;
        }
    // cross-wave reduce via LDS scratch (dead A-buf): [128 rows][4 wn][2 f32]
    if (l16 == 0) {
#pragma unroll
        for (int i = 0; i < 4; ++i)
#pragma unroll
            for (int r = 0; r < 4; ++r) {
                int row_l = wm * 64 + i * 16 + quad * 4 + r;
                *(float*)(smem + row_l * 32 + wn * 8) = ps[i][r];
                *(float*)(smem + row_l * 32 + wn * 8 + 4) = ps2[i][r];
            }
    }
    __syncthreads();
    // per-i: LN1 + 16x128 transpose-store of bf16 x1 into srcb[1024:2048)
    const uint32_t sb = 24576u + (uint32_t)w * 4096u;  // dead B region
#pragma unroll
    for (int i = 0; i < 4; ++i) {
#pragma unroll
        for (int r = 0; r < 4; ++r) {
            int row_l = wm * 64 + i * 16 + quad * 4 + r;
            float S = 0.f, S2 = 0.f;
#pragma unroll
            for (int w4 = 0; w4 < 4; ++w4) {
                S += *(const float*)(smem + row_l * 32 + w4 * 8);
                S2 += *(const float*)(smem + row_l * 32 + w4 * 8 + 4);
            }
            float mu = S * (1.0f / 512.0f);
            float var = S2 * (1.0f / 512.0f) - mu * mu;
            float rstd = rsqrtf(var + 1e-5f);
#pragma unroll
            for (int nt = 0; nt < 8; ++nt) {
                int col = wn * 128 + nt * 16 + l16;
                float v = (acc[i][nt][r] - mu) * rstd * g1[col] + be1[col];
                *(bf16*)(smem + swz(sb, quad * 4 + r, 256, (nt * 16 + l16) * 2)) = (bf16)v;
            }
        }
        asm volatile("s_waitcnt lgkmcnt(0)" ::: "memory");
#pragma unroll
        for (int j = 0; j < 4; ++j) {
            int uu = j * 64 + lane;
            int row = uu >> 4, ch = uu & 15;
            bf16x8 v = *(bf16x8*)(smem + swz(sb, row, 256, ch * 16));
            *(bf16x8*)(srcb + (size_t)(mb * 128 + wm * 64 + i * 16 + row) * 2048 + 1024 +
                       wn * 256 + ch * 16) = v;
        }
        asm volatile("s_waitcnt lgkmcnt(0)" ::: "memory");
    }
}

// ---------- FF1 v4: M=32768 N=2048 K=512; 128x512 tile, grid (256,4) ----------
// 3-deep pipelined; epilogue bias+relu -> 3-region transpose-store.
extern "C" __global__ __launch_bounds__(512, 2)
void ff1_kernel(char* __restrict__ srcb, const char* __restrict__ W1p,
                const float* __restrict__ b1, char* __restrict__ doutb,
                char* __restrict__ wsOb) {
    extern __shared__ char smem[];
    const int tid = threadIdx.x;
    const int w = tid >> 6, lane = tid & 63, l16 = lane & 15, quad = lane >> 4;
    const int wm = w >> 2, wn = w & 3;
    const int mb = blockIdx.x, cb = blockIdx.y;

    f32x4 acc[4][8];
#pragma unroll
    for (int i = 0; i < 4; ++i)
#pragma unroll
        for (int nt = 0; nt < 8; ++nt) acc[i][nt] = (f32x4){0.f, 0.f, 0.f, 0.f};

#define FF1_STAGE(ib, t)                                                               \
    {                                                                                  \
        int ca = w >> 1, rg = w & 1; /* A: 8 wave-issues (gathered rows) */            \
        gload16(srcb + (size_t)(mb * 128 + rg * 64 + lane) * 2048 + 1024 + (t) * 64 + ca * 16, \
                smem + (uint32_t)(ib) * 8192u + ca * 2048 + rg * 1024);                \
        _Pragma("unroll")                                                              \
        for (int j = 0; j < 4; ++j) { /* B: 32 wave-issues, contiguous 1KB each */     \
            int idx = w * 4 + j, c = idx >> 3, ng = idx & 7;                           \
            gload16(W1p + (size_t)(cb * 16 + (t)) * 32768 + c * 8192 + ng * 1024 + lane * 16, \
                    smem + 24576u + (uint32_t)(ib) * 32768u + (uint32_t)c * 8192 + (uint32_t)ng * 1024); \
        }                                                                              \
    }

    FF1_STAGE(0, 0);
    FF1_STAGE(1, 1);
    asm volatile("s_waitcnt vmcnt(5)" ::: "memory");
    __builtin_amdgcn_s_barrier();

    int ib = 0;
#pragma unroll 1
    for (int t = 0; t < 16; ++t) {
        int in2 = ib + 2; if (in2 >= 3) in2 -= 3;
        if (t + 2 < 16) FF1_STAGE(in2, t + 2);
        const uint32_t A0 = (uint32_t)ib * 8192u;
        const uint32_t B0 = 24576u + (uint32_t)ib * 32768u;
        bf16x8 a[4];
#pragma unroll
        for (int i = 0; i < 4; ++i)
            a[i] = *(const bf16x8*)(smem + A0 + quad * 2048 + (wm * 64 + i * 16 + l16) * 16);
#pragma unroll
        for (int nt = 0; nt < 8; ++nt) {
            bf16x8 b = *(const bf16x8*)(smem + B0 + quad * 8192 + (wn * 128 + nt * 16 + l16) * 16);
#pragma unroll
            for (int i = 0; i < 4; ++i) acc[i][nt] = MFMA16(a[i], b, acc[i][nt]);
        }
        if (t + 2 < 16) asm volatile("s_waitcnt vmcnt(5)" ::: "memory");
        else            asm volatile("s_waitcnt vmcnt(0)" ::: "memory");
        __builtin_amdgcn_s_barrier();
        ib = (ib == 2) ? 0 : ib + 1;
    }
#undef FF1_STAGE

    // epilogue: bias+relu; per-i 16x128-col transpose through 4KB wave scratch
    const uint32_t sb = 24576u + (uint32_t)w * 4096u;  // dead B region
#pragma unroll
    for (int i = 0; i < 4; ++i) {
#pragma unroll
        for (int nt = 0; nt < 8; ++nt) {
            float bb = b1[cb * 512 + wn * 128 + nt * 16 + l16];
#pragma unroll
            for (int r = 0; r < 4; ++r)
                *(bf16*)(smem + swz(sb, quad * 4 + r, 256, (nt * 16 + l16) * 2)) =
                    (bf16)fmaxf(acc[i][nt][r] + bb, 0.0f);
        }
        asm volatile("s_waitcnt lgkmcnt(0)" ::: "memory");
#pragma unroll
        for (int j = 0; j < 4; ++j) {
            int uu = j * 64 + lane;  // 0..255: 16 rows x 16 chunks
            int row = uu >> 4, ch = uu & 15;
            bf16x8 v = *(bf16x8*)(smem + swz(sb, row, 256, ch * 16));
            size_t row_g = (size_t)(mb * 128 + wm * 64 + i * 16 + row);
            int nb2 = wn * 256 + ch * 16;  // byte within this cb's 1024B col-slice
            if (cb < 2)       *(bf16x8*)(doutb + row_g * 2048 + cb * 1024 + nb2) = v;
            else if (cb == 2) *(bf16x8*)(srcb + row_g * 2048 + nb2) = v;
            else              *(bf16x8*)(wsOb + row_g * 1024 + nb2) = v;
        }
        asm volatile("s_waitcnt lgkmcnt(0)" ::: "memory");
    }
}

// ---------- FF2 v6 + residual + LN2: M=32768 N=512 K=2048 -> f32 out ----------
// 3-deep pipelined, counted vmcnt(5); 128x512 tile (grid 256), BK=32, 64 iters.
extern "C" __global__ __launch_bounds__(512, 2)
void ff2_kernel(char* __restrict__ doutb, const char* __restrict__ srcb,
                const char* __restrict__ wsOb, const char* __restrict__ W2p,
                const float* __restrict__ b2, const float* __restrict__ g2,
                const float* __restrict__ be2) {
    extern __shared__ char smem[];
    const int tid = threadIdx.x;
    const int w = tid >> 6, lane = tid & 63, l16 = lane & 15, quad = lane >> 4;
    const int wm = w >> 2, wn = w & 3;
    const int mb = blockIdx.x;

    f32x4 acc[4][8];
#pragma unroll
    for (int i = 0; i < 4; ++i)
#pragma unroll
        for (int nt = 0; nt < 8; ++nt) acc[i][nt] = (f32x4){0.f, 0.f, 0.f, 0.f};

#define FF2_STAGE(ib, t)                                                               \
    {                                                                                  \
        const char* hb; int rstride, koffb;                                            \
        if ((t) < 32)      { hb = doutb; rstride = 2048; koffb = (t) * 64; }           \
        else if ((t) < 48) { hb = srcb;  rstride = 2048; koffb = ((t) - 32) * 64; }    \
        else               { hb = wsOb;  rstride = 1024; koffb = ((t) - 48) * 64; }    \
        int ca = w >> 1, rg = w & 1; /* A: 8 wave-issues (gathered h rows) */          \
        gload16(hb + (size_t)(mb * 128 + rg * 64 + lane) * rstride + koffb + ca * 16,  \
                smem + (uint32_t)(ib) * 8192u + ca * 2048 + rg * 1024);                \
        _Pragma("unroll")                                                              \
        for (int j = 0; j < 4; ++j) { /* B: 32 wave-issues, contiguous 1KB each */     \
            int idx = w * 4 + j, c = idx >> 3, ng = idx & 7;                           \
            gload16(W2p + (size_t)(t) * 32768 + c * 8192 + ng * 1024 + lane * 16,      \
                    smem + 24576u + (uint32_t)(ib) * 32768u + (uint32_t)c * 8192 + (uint32_t)ng * 1024); \
        }                                                                              \
    }

    FF2_STAGE(0, 0);
    FF2_STAGE(1, 1);
    asm volatile("s_waitcnt vmcnt(5)" ::: "memory");
    __builtin_amdgcn_s_barrier();

    int ib = 0;
#pragma unroll 1
    for (int t = 0; t < 64; ++t) {
        int in2 = ib + 2; if (in2 >= 3) in2 -= 3;
        if (t + 2 < 64) FF2_STAGE(in2, t + 2);
        const uint32_t A0 = (uint32_t)ib * 8192u;
        const uint32_t B0 = 24576u + (uint32_t)ib * 32768u;
        bf16x8 a[4];
#pragma unroll
        for (int i = 0; i < 4; ++i)
            a[i] = *(const bf16x8*)(smem + A0 + quad * 2048 + (wm * 64 + i * 16 + l16) * 16);
#pragma unroll
        for (int nt = 0; nt < 8; ++nt) {
            bf16x8 b = *(const bf16x8*)(smem + B0 + quad * 8192 + (wn * 128 + nt * 16 + l16) * 16);
#pragma unroll
            for (int i = 0; i < 4; ++i) acc[i][nt] = MFMA16(a[i], b, acc[i][nt]);
        }
        if (t + 2 < 64) asm volatile("s_waitcnt vmcnt(5)" ::: "memory");
        else            asm volatile("s_waitcnt vmcnt(0)" ::: "memory");
        __builtin_amdgcn_s_barrier();
        ib = (ib == 2) ? 0 : ib + 1;
    }
#undef FF2_STAGE

    // ---- epilogue: bias + residual(x1) + LN2 over full 512-col rows ----
#pragma unroll
    for (int nt = 0; nt < 8; ++nt) {
        int col = wn * 128 + nt * 16 + l16;
        float bb = b2[col];
#pragma unroll
        for (int i = 0; i < 4; ++i)
#pragma unroll
            for (int r = 0; r < 4; ++r) {
                int row = mb * 128 + wm * 64 + i * 16 + quad * 4 + r;
                float x1v = (float)*(const bf16*)(srcb + (size_t)row * 2048 + 1024 + col * 2);
                acc[i][nt][r] += bb + x1v;
            }
    }
    // per-(row, wave) partials over this wave's 128 cols
    float ps[4][4], ps2[4][4];
#pragma unroll
    for (int i = 0; i < 4; ++i)
#pragma unroll
        for (int r = 0; r < 4; ++r) {
            float s = 0.f, s2 = 0.f;
#pragma unroll
            for (int nt = 0; nt < 8; ++nt) {
                float v = acc[i][nt][r];
                s += v;
                s2 += v * v;
            }
#pragma unroll
            for (int sft = 1; sft < 16; sft <<= 1) {
                s += __shfl_xor(s, sft, 64);
                s2 += __shfl_xor(s2, sft, 64);
            }
            ps[i][r] = s;
            ps2[i][r] = s2;
        }
    // cross-wave reduce via LDS scratch (A-buf region dead): [128 rows][4 wn][2 f32]
    if (l16 == 0) {
#pragma unroll
        for (int i = 0; i < 4; ++i)
#pragma unroll
            for (int r = 0; r < 4; ++r) {
                int row_l = wm * 64 + i * 16 + quad * 4 + r;
                *(float*)(smem + row_l * 32 + wn * 8) = ps[i][r];
                *(float*)(smem + row_l * 32 + wn * 8 + 4) = ps2[i][r];
            }
    }
    __syncthreads();
#pragma unroll
    for (int i = 0; i < 4; ++i)
#pragma unroll
        for (int r = 0; r < 4; ++r) {
            int row_l = wm * 64 + i * 16 + quad * 4 + r;
            float S = 0.f, S2 = 0.f;
#pragma unroll
            for (int w4 = 0; w4 < 4; ++w4) {
                S += *(const float*)(smem + row_l * 32 + w4 * 8);
                S2 += *(const float*)(smem + row_l * 32 + w4 * 8 + 4);
            }
            float mu = S * (1.0f / 512.0f);
            float var = S2 * (1.0f / 512.0f) - mu * mu;
            float rstd = rsqrtf(var + 1e-5f);
            size_t row = (size_t)(mb * 128 + row_l);
#pragma unroll
            for (int nt = 0; nt < 8; ++nt) {
                int col = wn * 128 + nt * 16 + l16;
                *(float*)(doutb + row * 2048 + col * 4) =
                    (acc[i][nt][r] - mu) * rstd * g2[col] + be2[col];
            }
        }
}

extern "C" void kernel_launch(void* const* d_in, const int* in_sizes, int n_in,
                              void* d_out, int out_size, void* d_ws, size_t ws_size,
                              hipStream_t stream) {
    (void)in_sizes; (void)n_in; (void)out_size; (void)ws_size;
    float* src = (float*)d_in[0];
    const float* ipw = (const float*)d_in[1];
    const float* ipb = (const float*)d_in[2];
    const float* ow  = (const float*)d_in[3];
    const float* ob  = (const float*)d_in[4];
    const float* g1  = (const float*)d_in[5];
    const float* be1 = (const float*)d_in[6];
    const float* w1  = (const float*)d_in[7];
    const float* b1  = (const float*)d_in[8];
    const float* w2  = (const float*)d_in[9];
    const float* b2  = (const float*)d_in[10];
    const float* g2  = (const float*)d_in[11];
    const float* be2 = (const float*)d_in[12];
    bf16* ws = (bf16*)d_ws;
    char* srcb = (char*)src;
    char* doutb = (char*)d_out;
    char* qOb = (char*)d_ws + 6291456;  // 33.5 MB q/O/h-tail region

    wcvt_kernel<<<1536, 256, 0, stream>>>(ipw, ow, w1, w2, ws);
    xcvt_kernel<<<8192, 256, 0, stream>>>(src);

    hipFuncSetAttribute((const void*)qkv_kernel, hipFuncAttributeMaxDynamicSharedMemorySize, 122880);
    hipFuncSetAttribute((const void*)attn_kernel, hipFuncAttributeMaxDynamicSharedMemorySize, 32768);
    hipFuncSetAttribute((const void*)outproj_kernel, hipFuncAttributeMaxDynamicSharedMemorySize, 122880);
    hipFuncSetAttribute((const void*)ff1_kernel, hipFuncAttributeMaxDynamicSharedMemorySize, 122880);
    hipFuncSetAttribute((const void*)ff2_kernel, hipFuncAttributeMaxDynamicSharedMemorySize, 122880);

    qkv_kernel<<<dim3(256, 3), 512, 122880, stream>>>(srcb, (const char*)ws, ipb, qOb, doutb);
    attn_kernel<<<2048, 512, 32768, stream>>>(qOb, doutb);
    outproj_kernel<<<256, 512, 122880, stream>>>(srcb, qOb, (const char*)(ws + 786432), ob, g1, be1);
    ff1_kernel<<<dim3(256, 4), 512, 122880, stream>>>(srcb, (const char*)(ws + 1048576), b1, doutb, qOb);
    ff2_kernel<<<256, 512, 122880, stream>>>(doutb, srcb, qOb, (const char*)(ws + 2097152), b2, g2, be2);
}